// Round 12
// baseline (14692.859 us; speedup 1.0000x reference)
//
#include <hip/hip_runtime.h>
#include <hip/hip_bf16.h>

using bf16x8 = __attribute__((ext_vector_type(8))) short;  // 8 bf16, 4 VGPRs
using f32x4  = __attribute__((ext_vector_type(4))) float;

static constexpr int NB = 64, NT = 256, NE = 1024, NH = 1024, NL = 3;
static constexpr int NR = 4096, KC = 2048;
static constexpr int STATE = NL * NB * NH;             // 196608
static constexpr size_t WCAT_E = (size_t)NL * NR * KC;  // 25,165,824 bf16
static constexpr size_t XBF_E  = (size_t)NT * NB * NE;  // 16,777,216 bf16
static constexpr size_t HBUF_E = (size_t)STATE;
static constexpr int GATES_N = NB * NR;                // fallback path
static constexpr int FSTR  = 32;                       // u32s per flag slot (128B line)
static constexpr int NFLAG = 256 * FSTR;               // arrival flags
static constexpr int NREL  = 32 * FSTR;                // release flags
static constexpr size_t FLAGS_W = 2 * (NFLAG + NREL);  // main + probe regions

// ---------------- prologue kernels ----------------

__global__ void __launch_bounds__(256)
convert_w(const float* __restrict__ wih, const float* __restrict__ whh,
          __hip_bfloat16* __restrict__ wcat) {
    size_t i = (size_t)blockIdx.x * 256 + threadIdx.x;
    const size_t stride = (size_t)gridDim.x * 256;
    for (; i < WCAT_E; i += stride) {
        const int k = (int)(i & (KC - 1));
        const size_t lr = i >> 11;            // l*NR + r
        const int r = (int)(lr & (NR - 1));
        const int l = (int)(lr >> 12);
        const float v = (k < NE) ? wih[((size_t)l * NR + r) * NE + k]
                                 : whh[((size_t)l * NR + r) * NH + (k - NE)];
        wcat[i] = __float2bfloat16(v);
    }
}

__global__ void __launch_bounds__(256)
convert_x(const float* __restrict__ x, __hip_bfloat16* __restrict__ xbf) {
    size_t i = (size_t)blockIdx.x * 256 + threadIdx.x;
    const size_t stride = (size_t)gridDim.x * 256;
    for (; i < XBF_E; i += stride) {          // xbf[t][m][e] <- x[m][t][e]
        const int e = (int)(i & (NE - 1));
        const size_t tm = i >> 10;
        const int m = (int)(tm & (NB - 1));
        const int t = (int)(tm >> 6);
        xbf[i] = __float2bfloat16(x[((size_t)m * NT + t) * NE + e]);
    }
}

__global__ void __launch_bounds__(256)
init_h(const float* __restrict__ enc, __hip_bfloat16* __restrict__ hA,
       unsigned* __restrict__ flags) {
    const int i = blockIdx.x * 256 + threadIdx.x;     // 768 blocks
    if (i < STATE) hA[i] = __float2bfloat16(enc[i & (NB * NH - 1)]);
    if (i < (int)FLAGS_W) flags[i] = 0u;
}

// ---------------- sc1 (agent-coherent) helpers ----------------

__device__ __forceinline__ unsigned long long aload64(const void* p) {
    return __hip_atomic_load((const unsigned long long*)p,
                             __ATOMIC_RELAXED, __HIP_MEMORY_SCOPE_AGENT);
}
union FragU { unsigned long long u[2]; bf16x8 v; };
__device__ __forceinline__ bf16x8 aload_frag(const __hip_bfloat16* p) {
    FragU x;
    x.u[0] = aload64(p);
    x.u[1] = aload64(p + 4);
    return x.v;
}
__device__ __forceinline__ unsigned short bf16bits(float f) {
    const __hip_bfloat16 h = __float2bfloat16(f);
    union { __hip_bfloat16 h; unsigned short s; } u{h};
    return u.s;
}

// ---------------- root-poll barrier with replicated release ----------------
// Arrival: flag on own 128B line. Root (bid 0) polls all 256 with 4 waves,
// then posts 32 replicated release flags; block b polls release[b>>3] only
// (8 readers/line -> no MALL hot-spot). All relaxed agent atomics; data
// ordering from vmcnt(0) before flag store (sc1 write-through data path).
__device__ __forceinline__ void grid_barrier(unsigned* __restrict__ flags,
                                             unsigned* __restrict__ release,
                                             int bid, int tid, unsigned gen) {
    asm volatile("s_waitcnt vmcnt(0)" ::: "memory");
    __syncthreads();
    if (tid == 0)
        __hip_atomic_store(&flags[bid * FSTR], gen,
                           __ATOMIC_RELAXED, __HIP_MEMORY_SCOPE_AGENT);
    if (bid == 0) {
        // root: 4 waves x 64 lanes -> one flag per thread
        for (;;) {
            const unsigned v = __hip_atomic_load(&flags[tid * FSTR],
                                  __ATOMIC_RELAXED, __HIP_MEMORY_SCOPE_AGENT);
            if (__all((int)(v >= gen))) break;
            __builtin_amdgcn_s_sleep(2);
        }
        __syncthreads();                      // all 4 root waves done polling
        const int lane = tid & 63, wv = tid >> 6;
        if (lane < 8)
            __hip_atomic_store(&release[(wv * 8 + lane) * FSTR], gen,
                               __ATOMIC_RELAXED, __HIP_MEMORY_SCOPE_AGENT);
    } else {
        if (tid < 64) {
            for (;;) {
                const unsigned v = __hip_atomic_load(&release[(bid >> 3) * FSTR],
                                      __ATOMIC_RELAXED, __HIP_MEMORY_SCOPE_AGENT);
                if (v >= gen) break;
                __builtin_amdgcn_s_sleep(2);
            }
        }
        __syncthreads();
    }
}

// ---------------- barrier microprobe: dur_us / 128 == cost of one barrier --
__global__ void __launch_bounds__(256, 1)
barrier_probe(unsigned* __restrict__ flags, unsigned* __restrict__ release) {
    for (unsigned gen = 1; gen <= 128; ++gen)
        grid_barrier(flags, release, blockIdx.x, threadIdx.x, gen);
}

// ---------------- persistent MFMA kernel (NORMAL launch, grid=256) --------
__global__ void __launch_bounds__(256, 1)
lstm_mfma(const float* __restrict__ bias,
          const __hip_bfloat16* __restrict__ wcat,
          const __hip_bfloat16* __restrict__ xbf,
          __hip_bfloat16* __restrict__ hA,
          __hip_bfloat16* __restrict__ hB,
          float* __restrict__ out,
          unsigned* __restrict__ flags)
{
    const int tid  = threadIdx.x;
    const int lane = tid & 63;
    const int wv   = tid >> 6;            // K-slice 0..3
    const int bid  = blockIdx.x;
    const int U0   = bid * 4;
    const int nfr  = lane & 15;           // frag col: g = nfr>>2, u = nfr&3
    const int kgrp = (lane >> 4) * 8;     // frag k-offset within 32
    const int mgrp = (lane >> 4) * 4;     // D-frag row group
    const int cm   = tid >> 1;            // cell: batch (tid<128)
    const int cp   = (tid & 1) * 2;       // cell: unit pair offset (0 or 2)

    float* hT   = out;
    float* cT   = out + STATE;
    float* outs = out + 2 * STATE;
    unsigned* release = flags + NFLAG;

    __shared__ float part[4][4][16][17];  // [kslice][mtile][n][m] padded

    // ---- preload this wave's B fragments for all 3 layers ----
    const int row   = (nfr >> 2) * NH + U0 + (nfr & 3);     // gate row
    const int kbase = (wv >= 2 ? 1024 : 0) + (wv & 1) * 512 + kgrp;
    bf16x8 b0[16], b1[16], b2[16];
    {
        const __hip_bfloat16* w0 = wcat + ((size_t)0 * NR + row) * KC + kbase;
        const __hip_bfloat16* w1 = wcat + ((size_t)1 * NR + row) * KC + kbase;
        const __hip_bfloat16* w2 = wcat + ((size_t)2 * NR + row) * KC + kbase;
        #pragma unroll
        for (int kb = 0; kb < 16; ++kb) {
            b0[kb] = *(const bf16x8*)(w0 + kb * 32);
            b1[kb] = *(const bf16x8*)(w1 + kb * 32);
            b2[kb] = *(const bf16x8*)(w2 + kb * 32);
        }
    }

    float c0a = 0.f, c0b = 0.f, c1a = 0.f, c1b = 0.f, c2a = 0.f, c2b = 0.f;
    unsigned gen = 1;

    auto stage = [&](const __hip_bfloat16* a1, const __hip_bfloat16* a2,
                     bool a1cached, const bf16x8 (&b)[16], const float* bias_l,
                     float& cA, float& cB, __hip_bfloat16* hcur_l,
                     int t, bool is_top, bool last_t,
                     float* hT_l, float* cT_l) {
        const __hip_bfloat16* apart = (wv < 2) ? a1 : a2;
        const bool cached = (wv < 2) ? a1cached : false;
        const int aoff = (wv & 1) * 512 + kgrp;
        f32x4 acc[4];
        #pragma unroll
        for (int mt = 0; mt < 4; ++mt) acc[mt] = f32x4{0.f, 0.f, 0.f, 0.f};
        if (cached) {
            #pragma unroll
            for (int mt = 0; mt < 4; ++mt) {
                const __hip_bfloat16* ar = apart + (size_t)(mt * 16 + nfr) * 1024 + aoff;
                #pragma unroll
                for (int kb = 0; kb < 16; ++kb)
                    acc[mt] = __builtin_amdgcn_mfma_f32_16x16x32_bf16(
                        *(const bf16x8*)(ar + kb * 32), b[kb], acc[mt], 0, 0, 0);
            }
        } else {
            #pragma unroll
            for (int mt = 0; mt < 4; ++mt) {
                const __hip_bfloat16* ar = apart + (size_t)(mt * 16 + nfr) * 1024 + aoff;
                #pragma unroll
                for (int kb = 0; kb < 16; ++kb)
                    acc[mt] = __builtin_amdgcn_mfma_f32_16x16x32_bf16(
                        aload_frag(ar + kb * 32), b[kb], acc[mt], 0, 0, 0);
            }
        }
        #pragma unroll
        for (int mt = 0; mt < 4; ++mt)
            #pragma unroll
            for (int j = 0; j < 4; ++j)
                part[wv][mt][nfr][mgrp + j] = acc[mt][j];
        __syncthreads();

        if (tid < 128) {                   // 2 adjacent units per thread
            float hn2[2], cn2[2];
            #pragma unroll
            for (int j = 0; j < 2; ++j) {
                const int ul = cp + j;
                const int cunit = U0 + ul;
                float gv[4];
                #pragma unroll
                for (int g = 0; g < 4; ++g) {
                    float s = bias_l[g * NH + cunit];
                    #pragma unroll
                    for (int w2 = 0; w2 < 4; ++w2)
                        s += part[w2][cm >> 4][g * 4 + ul][cm & 15];
                    gv[g] = s;
                }
                const float iv = 1.f / (1.f + __expf(-gv[0]));
                const float fv = 1.f / (1.f + __expf(-gv[1]));
                const float gg = 1.f - 2.f / (__expf(2.f * gv[2]) + 1.f);
                const float ov = 1.f / (1.f + __expf(-gv[3]));
                float& cref = (j == 0) ? cA : cB;
                const float cn = fv * cref + iv * gg;
                const float hn = ov * (1.f - 2.f / (__expf(2.f * cn) + 1.f));
                cref = cn;
                hn2[j] = hn; cn2[j] = cn;
            }
            const unsigned pk = (unsigned)bf16bits(hn2[0]) |
                                ((unsigned)bf16bits(hn2[1]) << 16);
            __hip_atomic_store((unsigned*)(hcur_l + cm * NH + U0 + cp), pk,
                               __ATOMIC_RELAXED, __HIP_MEMORY_SCOPE_AGENT);
            if (is_top) {
                outs[((size_t)cm * NT + t) * NH + U0 + cp]     = hn2[0];
                outs[((size_t)cm * NT + t) * NH + U0 + cp + 1] = hn2[1];
            }
            if (last_t) {
                hT_l[cm * NH + U0 + cp]     = hn2[0];
                hT_l[cm * NH + U0 + cp + 1] = hn2[1];
                cT_l[cm * NH + U0 + cp]     = cn2[0];
                cT_l[cm * NH + U0 + cp + 1] = cn2[1];
            }
        }
    };

    for (int t = 0; t < NT; ++t) {
        const __hip_bfloat16* hprev = (t & 1) ? hB : hA;
        __hip_bfloat16*       hcur  = (t & 1) ? hA : hB;
        const bool last_t = (t == NT - 1);

        stage(xbf + (size_t)t * NB * NE, hprev, true, b0, bias,
              c0a, c0b, hcur, t, false, last_t, hT, cT);             // l=0
        grid_barrier(flags, release, bid, tid, gen++);

        stage(hcur, hprev + NB * NH, false, b1, bias + NR,
              c1a, c1b, hcur + NB * NH, t, false, last_t,
              hT + NB * NH, cT + NB * NH);                           // l=1
        grid_barrier(flags, release, bid, tid, gen++);

        stage(hcur + NB * NH, hprev + 2 * NB * NH, false, b2, bias + 2 * NR,
              c2a, c2b, hcur + 2 * NB * NH, t, true, last_t,
              hT + 2 * NB * NH, cT + 2 * NB * NH);                   // l=2
        // no barrier after l=2: t+1's l0/l1 barriers separate all RAW/WAR.
    }
}

// ---------------- fp32 fallback path (R6, proven) ----------------

__device__ __forceinline__ float sigf(float x) { return 1.0f / (1.0f + __expf(-x)); }
__device__ __forceinline__ float tanh_(float x) {
    return 1.0f - 2.0f / (__expf(2.0f * x) + 1.0f);
}

__global__ void __launch_bounds__(512)
init_kernel(const float* __restrict__ enc, float* __restrict__ out,
            float* __restrict__ gates) {
    float* hbA = out;
    float* cTf = out + STATE;
    const int idx = blockIdx.x * 512 + threadIdx.x;
    for (int i = idx; i < STATE; i += 131072) {
        hbA[i] = enc[i & 65535];
        cTf[i] = 0.0f;
    }
    for (int i = idx; i < GATES_N; i += 131072) gates[i] = 0.0f;
}

__global__ void __launch_bounds__(512)
gates_kernel(const float* __restrict__ xbase, long xstr,
             const float* __restrict__ hbase,
             const float* __restrict__ wih, const float* __restrict__ whh,
             float* __restrict__ gates)
{
    const int tid  = threadIdx.x;
    const int lane = tid & 63;
    const int w    = tid >> 6;
    const int bid  = blockIdx.x;
    const int ng   = bid >> 3;
    const int ks   = bid & 7;
    const int r0   = ng * 64;
    const int b0   = w * 8;

    __shared__ float4 tile[2][8][64];

    const float* wbase; const float* ab; long astr; int kc0;
    if (ks < 4) { wbase = wih; kc0 = ks * 256;       ab = xbase + kc0; astr = xstr; }
    else        { wbase = whh; kc0 = (ks - 4) * 256; ab = hbase + kc0; astr = 1024; }

    const float* pb[8];
    #pragma unroll
    for (int i = 0; i < 8; ++i) pb[i] = ab + (size_t)(b0 + i) * astr;

    float acc[8] = {0, 0, 0, 0, 0, 0, 0, 0};
    const int sq = tid & 7, sr = tid >> 3;
    const float* wrow = wbase + (size_t)(r0 + sr) * 1024 + kc0;
    tile[0][sq][sr ^ sq] = *(const float4*)(wrow + sq * 4);

    for (int c = 0; c < 8; ++c) {
        __syncthreads();
        if (c + 1 < 8)
            tile[(c + 1) & 1][sq][sr ^ sq] =
                *(const float4*)(wrow + (c + 1) * 32 + sq * 4);
        #pragma unroll
        for (int q = 0; q < 8; ++q) {
            const float4 wq = tile[c & 1][q][lane ^ q];
            #pragma unroll
            for (int i = 0; i < 8; ++i) {
                const float4 aq = *(const float4*)(pb[i] + c * 32 + q * 4);
                acc[i] = fmaf(aq.x, wq.x, acc[i]);
                acc[i] = fmaf(aq.y, wq.y, acc[i]);
                acc[i] = fmaf(aq.z, wq.z, acc[i]);
                acc[i] = fmaf(aq.w, wq.w, acc[i]);
            }
        }
    }
    #pragma unroll
    for (int i = 0; i < 8; ++i)
        atomicAdd(&gates[((size_t)(b0 + i) << 12) + r0 + lane], acc[i]);
}

__global__ void __launch_bounds__(512)
cell_kernel(const float* __restrict__ bias_l, float* __restrict__ gates,
            float* __restrict__ cT_l, float* __restrict__ hcur_l,
            float* __restrict__ outs_t, int is_last)
{
    const int g  = blockIdx.x * 512 + threadIdx.x;
    const int b  = g >> 10, nl = g & 1023;
    float gv[4];
    #pragma unroll
    for (int gi = 0; gi < 4; ++gi) {
        const size_t gidx = ((size_t)b << 12) + gi * 1024 + nl;
        gv[gi] = bias_l[gi * 1024 + nl] + gates[gidx];
        gates[gidx] = 0.0f;
    }
    const int si = b * 1024 + nl;
    const float cn = sigf(gv[1]) * cT_l[si] + sigf(gv[0]) * tanh_(gv[2]);
    const float hn = sigf(gv[3]) * tanh_(cn);
    cT_l[si]   = cn;
    hcur_l[si] = hn;
    if (is_last) outs_t[(size_t)b * (NT * NH) + nl] = hn;
}

// ---------------- launcher ----------------

extern "C" void kernel_launch(void* const* d_in, const int* in_sizes, int n_in,
                              void* d_out, int out_size, void* d_ws, size_t ws_size,
                              hipStream_t stream) {
    const float* inputs = (const float*)d_in[0];
    const float* enc    = (const float*)d_in[1];
    const float* W_ih   = (const float*)d_in[2];
    const float* W_hh   = (const float*)d_in[3];
    const float* bias   = (const float*)d_in[4];
    float* out = (float*)d_out;

    const size_t need = (WCAT_E + XBF_E + 2 * HBUF_E) * 2 + FLAGS_W * 4;
    if (ws_size >= need) {
        __hip_bfloat16* wcat = (__hip_bfloat16*)d_ws;
        __hip_bfloat16* xbf  = wcat + WCAT_E;
        __hip_bfloat16* hA   = xbf + XBF_E;
        __hip_bfloat16* hB   = hA + HBUF_E;
        unsigned*       flags = (unsigned*)(hB + HBUF_E);
        unsigned*       pflags = flags + NFLAG + NREL;   // probe region

        convert_w<<<dim3(4096), dim3(256), 0, stream>>>(W_ih, W_hh, wcat);
        convert_x<<<dim3(2048), dim3(256), 0, stream>>>(inputs, xbf);
        init_h<<<dim3(768), dim3(256), 0, stream>>>(enc, hA, flags);

        // barrier microprobe: rocprof dur_us / 128 = per-barrier cost
        barrier_probe<<<dim3(256), dim3(256), 0, stream>>>(pflags, pflags + NFLAG);

        lstm_mfma<<<dim3(256), dim3(256), 0, stream>>>(
            bias, wcat, xbf, hA, hB, out, flags);
    } else {
        float* wsf   = (float*)d_ws;
        float* gates = wsf;
        float* hbB   = wsf + GATES_N;
        float* hbA   = out;
        float* cTf   = out + STATE;
        float* outs  = out + 2 * STATE;

        init_kernel<<<dim3(256), dim3(512), 0, stream>>>(enc, out, gates);
        for (int t = 0; t < NT; ++t) {
            float* hprev = (t & 1) ? hbB : hbA;
            float* hcur  = (t & 1) ? hbA : hbB;
            for (int l = 0; l < NL; ++l) {
                const float* xbase; long xstr;
                if (l == 0) { xbase = inputs + (size_t)t * NE;          xstr = (long)NT * NE; }
                else        { xbase = hcur + (size_t)(l - 1) * NB * NH; xstr = NH; }
                gates_kernel<<<dim3(512), dim3(512), 0, stream>>>(
                    xbase, xstr, hprev + (size_t)l * NB * NH,
                    W_ih + (size_t)l * NR * NE, W_hh + (size_t)l * NR * NH, gates);
                cell_kernel<<<dim3(128), dim3(512), 0, stream>>>(
                    bias + (size_t)l * NR, gates,
                    cTf + (size_t)l * NB * NH, hcur + (size_t)l * NB * NH,
                    outs + (size_t)t * NH, (l == NL - 1) ? 1 : 0);
            }
        }
    }
}

// Round 13
// 11920.992 us; speedup vs baseline: 1.2325x; 1.2325x over previous
//
#include <hip/hip_runtime.h>
#include <hip/hip_bf16.h>

using bf16x8 = __attribute__((ext_vector_type(8))) short;  // 8 bf16, 4 VGPRs
using f32x4  = __attribute__((ext_vector_type(4))) float;

static constexpr int NB = 64, NT = 256, NE = 1024, NH = 1024, NL = 3;
static constexpr int NR = 4096, KC = 2048;
static constexpr int STATE = NL * NB * NH;             // 196608
static constexpr int BH = NB * NH;                     // 65536
static constexpr size_t WCAT_E = (size_t)NL * NR * KC;  // 25,165,824 bf16
static constexpr size_t XBF_E  = (size_t)NT * NB * NE;  // 16,777,216 bf16
static constexpr size_t HSEQ_E = (size_t)(NT + 1) * STATE;  // 50,528,256 bf16
static constexpr size_t HBUF_E = (size_t)STATE;
static constexpr int FSTR  = 32;                       // u32s per flag slot (128B)
static constexpr int NFLAG = 256 * FSTR;
static constexpr int NREL  = 32 * FSTR;
static constexpr size_t FLAGS_W = NFLAG + NREL;

// ---------------- prologue kernels ----------------

__global__ void __launch_bounds__(256)
convert_w(const float* __restrict__ wih, const float* __restrict__ whh,
          __hip_bfloat16* __restrict__ wcat) {
    size_t i = (size_t)blockIdx.x * 256 + threadIdx.x;
    const size_t stride = (size_t)gridDim.x * 256;
    for (; i < WCAT_E; i += stride) {
        const int k = (int)(i & (KC - 1));
        const size_t lr = i >> 11;            // l*NR + r
        const int r = (int)(lr & (NR - 1));
        const int l = (int)(lr >> 12);
        const float v = (k < NE) ? wih[((size_t)l * NR + r) * NE + k]
                                 : whh[((size_t)l * NR + r) * NH + (k - NE)];
        wcat[i] = __float2bfloat16(v);
    }
}

__global__ void __launch_bounds__(256)
convert_x(const float* __restrict__ x, __hip_bfloat16* __restrict__ xbf) {
    size_t i = (size_t)blockIdx.x * 256 + threadIdx.x;
    const size_t stride = (size_t)gridDim.x * 256;
    for (; i < XBF_E; i += stride) {          // xbf[t][m][e] <- x[m][t][e]
        const int e = (int)(i & (NE - 1));
        const size_t tm = i >> 10;
        const int m = (int)(tm & (NB - 1));
        const int t = (int)(tm >> 6);
        xbf[i] = __float2bfloat16(x[((size_t)m * NT + t) * NE + e]);
    }
}

__global__ void __launch_bounds__(256)
init_h(const float* __restrict__ enc, __hip_bfloat16* __restrict__ h0,
       unsigned* __restrict__ flags) {
    const int i = blockIdx.x * 256 + threadIdx.x;     // 768 blocks
    if (i < STATE) h0[i] = __float2bfloat16(enc[i & (BH - 1)]);
    if (i < (int)FLAGS_W) flags[i] = 0u;
}

// ---------------- sc1 (agent-coherent) helpers ----------------

__device__ __forceinline__ unsigned long long aload64(const void* p) {
    return __hip_atomic_load((const unsigned long long*)p,
                             __ATOMIC_RELAXED, __HIP_MEMORY_SCOPE_AGENT);
}
union FragU { unsigned long long u[2]; bf16x8 v; };
__device__ __forceinline__ bf16x8 aload_frag(const __hip_bfloat16* p) {
    FragU x;
    x.u[0] = aload64(p);
    x.u[1] = aload64(p + 4);
    return x.v;
}
__device__ __forceinline__ unsigned short bf16bits(float f) {
    const __hip_bfloat16 h = __float2bfloat16(f);
    union { __hip_bfloat16 h; unsigned short s; } u{h};
    return u.s;
}

// ---------------- root-poll barrier (measured ~0.6us empty) ----------------
__device__ __forceinline__ void grid_barrier(unsigned* __restrict__ flags,
                                             unsigned* __restrict__ release,
                                             int bid, int tid, unsigned gen) {
    asm volatile("s_waitcnt vmcnt(0)" ::: "memory");
    __syncthreads();
    if (tid == 0)
        __hip_atomic_store(&flags[bid * FSTR], gen,
                           __ATOMIC_RELAXED, __HIP_MEMORY_SCOPE_AGENT);
    if (bid == 0) {
        for (;;) {
            const unsigned v = __hip_atomic_load(&flags[tid * FSTR],
                                  __ATOMIC_RELAXED, __HIP_MEMORY_SCOPE_AGENT);
            if (__all((int)(v >= gen))) break;
            __builtin_amdgcn_s_sleep(2);
        }
        __syncthreads();
        const int lane = tid & 63, wv = tid >> 6;
        if (lane < 8)
            __hip_atomic_store(&release[(wv * 8 + lane) * FSTR], gen,
                               __ATOMIC_RELAXED, __HIP_MEMORY_SCOPE_AGENT);
    } else {
        if (tid < 64) {
            for (;;) {
                const unsigned v = __hip_atomic_load(&release[(bid >> 3) * FSTR],
                                      __ATOMIC_RELAXED, __HIP_MEMORY_SCOPE_AGENT);
                if (v >= gen) break;
                __builtin_amdgcn_s_sleep(2);
            }
        }
        __syncthreads();
    }
}

// ---------------- rotating-buffer MFMA kernel (grid=256, normal launch) ----
// h(t) lives at hseq + t*STATE: addresses never reused -> reads are NORMAL
// cached loads (L2-shared per XCD); writes are sc1 write-through (visible at
// MALL, which fresh-address reads fetch from). No WAR hazards exist.
__global__ void __launch_bounds__(256, 1)
lstm_rot(const float* __restrict__ bias,
         const __hip_bfloat16* __restrict__ wcat,
         const __hip_bfloat16* __restrict__ xbf,
         __hip_bfloat16* __restrict__ hseq,
         float* __restrict__ out,
         unsigned* __restrict__ flags)
{
    const int tid  = threadIdx.x;
    const int lane = tid & 63;
    const int wv   = tid >> 6;            // K-slice 0..3
    const int bid  = blockIdx.x;
    const int U0   = bid * 4;
    const int nfr  = lane & 15;           // frag col: g = nfr>>2, u = nfr&3
    const int kgrp = (lane >> 4) * 8;
    const int mgrp = (lane >> 4) * 4;
    const int cm   = tid >> 1;            // cell: batch (tid<128)
    const int cp   = (tid & 1) * 2;       // cell: unit pair offset

    float* hT   = out;
    float* cT   = out + STATE;
    float* outs = out + 2 * STATE;
    unsigned* release = flags + NFLAG;

    __shared__ float part[4][4][16][17];

    const int row   = (nfr >> 2) * NH + U0 + (nfr & 3);
    const int kbase = (wv >= 2 ? 1024 : 0) + (wv & 1) * 512 + kgrp;
    bf16x8 b0[16], b1[16], b2[16];
    {
        const __hip_bfloat16* w0 = wcat + ((size_t)0 * NR + row) * KC + kbase;
        const __hip_bfloat16* w1 = wcat + ((size_t)1 * NR + row) * KC + kbase;
        const __hip_bfloat16* w2 = wcat + ((size_t)2 * NR + row) * KC + kbase;
        #pragma unroll
        for (int kb = 0; kb < 16; ++kb) {
            b0[kb] = *(const bf16x8*)(w0 + kb * 32);
            b1[kb] = *(const bf16x8*)(w1 + kb * 32);
            b2[kb] = *(const bf16x8*)(w2 + kb * 32);
        }
    }

    float c0a = 0.f, c0b = 0.f, c1a = 0.f, c1b = 0.f, c2a = 0.f, c2b = 0.f;
    unsigned gen = 1;

    auto stage = [&](const __hip_bfloat16* a1, const __hip_bfloat16* a2,
                     const bf16x8 (&b)[16], const float* bias_l,
                     float& cA, float& cB, __hip_bfloat16* hw,
                     int t, bool is_top, bool last_t,
                     float* hT_l, float* cT_l) {
        const __hip_bfloat16* apart = (wv < 2) ? a1 : a2;
        const int aoff = (wv & 1) * 512 + kgrp;
        f32x4 acc[4];
        #pragma unroll
        for (int mt = 0; mt < 4; ++mt) acc[mt] = f32x4{0.f, 0.f, 0.f, 0.f};
        #pragma unroll
        for (int mt = 0; mt < 4; ++mt) {
            const __hip_bfloat16* ar = apart + (size_t)(mt * 16 + nfr) * 1024 + aoff;
            #pragma unroll
            for (int kb = 0; kb < 16; ++kb)
                acc[mt] = __builtin_amdgcn_mfma_f32_16x16x32_bf16(
                    *(const bf16x8*)(ar + kb * 32), b[kb], acc[mt], 0, 0, 0);
        }
        #pragma unroll
        for (int mt = 0; mt < 4; ++mt)
            #pragma unroll
            for (int j = 0; j < 4; ++j)
                part[wv][mt][nfr][mgrp + j] = acc[mt][j];
        __syncthreads();

        if (tid < 128) {
            float hn2[2], cn2[2];
            #pragma unroll
            for (int j = 0; j < 2; ++j) {
                const int ul = cp + j;
                const int cunit = U0 + ul;
                float gv[4];
                #pragma unroll
                for (int g = 0; g < 4; ++g) {
                    float s = bias_l[g * NH + cunit];
                    #pragma unroll
                    for (int w2 = 0; w2 < 4; ++w2)
                        s += part[w2][cm >> 4][g * 4 + ul][cm & 15];
                    gv[g] = s;
                }
                const float iv = 1.f / (1.f + __expf(-gv[0]));
                const float fv = 1.f / (1.f + __expf(-gv[1]));
                const float gg = 1.f - 2.f / (__expf(2.f * gv[2]) + 1.f);
                const float ov = 1.f / (1.f + __expf(-gv[3]));
                float& cref = (j == 0) ? cA : cB;
                const float cn = fv * cref + iv * gg;
                const float hn = ov * (1.f - 2.f / (__expf(2.f * cn) + 1.f));
                cref = cn;
                hn2[j] = hn; cn2[j] = cn;
            }
            const unsigned pk = (unsigned)bf16bits(hn2[0]) |
                                ((unsigned)bf16bits(hn2[1]) << 16);
            __hip_atomic_store((unsigned*)(hw + cm * NH + U0 + cp), pk,
                               __ATOMIC_RELAXED, __HIP_MEMORY_SCOPE_AGENT);
            if (is_top) {
                outs[((size_t)cm * NT + t) * NH + U0 + cp]     = hn2[0];
                outs[((size_t)cm * NT + t) * NH + U0 + cp + 1] = hn2[1];
            }
            if (last_t) {
                hT_l[cm * NH + U0 + cp]     = hn2[0];
                hT_l[cm * NH + U0 + cp + 1] = hn2[1];
                cT_l[cm * NH + U0 + cp]     = cn2[0];
                cT_l[cm * NH + U0 + cp + 1] = cn2[1];
            }
        }
    };

    for (int t = 0; t < NT; ++t) {
        __hip_bfloat16* Hp = hseq + (size_t)t * STATE;        // h after t steps
        __hip_bfloat16* Hc = hseq + (size_t)(t + 1) * STATE;  // written this step
        const bool last_t = (t == NT - 1);

        stage(xbf + (size_t)t * NB * NE, Hp, b0, bias,
              c0a, c0b, Hc, t, false, last_t, hT, cT);               // l=0
        grid_barrier(flags, release, bid, tid, gen++);

        stage(Hc, Hp + BH, b1, bias + NR,
              c1a, c1b, Hc + BH, t, false, last_t,
              hT + BH, cT + BH);                                     // l=1
        grid_barrier(flags, release, bid, tid, gen++);

        stage(Hc + BH, Hp + 2 * BH, b2, bias + 2 * NR,
              c2a, c2b, Hc + 2 * BH, t, true, last_t,
              hT + 2 * BH, cT + 2 * BH);                             // l=2
        // no barrier needed after l=2: t+1's l0/l1 barriers cover all RAW;
        // rotation means no buffer is ever overwritten (no WAR at all).
    }
}

// ---------------- double-buffer sc1 fallback (R12 engine, proven) ----------
__global__ void __launch_bounds__(256, 1)
lstm_dbuf(const float* __restrict__ bias,
          const __hip_bfloat16* __restrict__ wcat,
          const __hip_bfloat16* __restrict__ xbf,
          __hip_bfloat16* __restrict__ hA,
          __hip_bfloat16* __restrict__ hB,
          float* __restrict__ out,
          unsigned* __restrict__ flags)
{
    const int tid  = threadIdx.x;
    const int lane = tid & 63;
    const int wv   = tid >> 6;
    const int bid  = blockIdx.x;
    const int U0   = bid * 4;
    const int nfr  = lane & 15;
    const int kgrp = (lane >> 4) * 8;
    const int mgrp = (lane >> 4) * 4;
    const int cm   = tid >> 1;
    const int cp   = (tid & 1) * 2;

    float* hT   = out;
    float* cT   = out + STATE;
    float* outs = out + 2 * STATE;
    unsigned* release = flags + NFLAG;

    __shared__ float part[4][4][16][17];

    const int row   = (nfr >> 2) * NH + U0 + (nfr & 3);
    const int kbase = (wv >= 2 ? 1024 : 0) + (wv & 1) * 512 + kgrp;
    bf16x8 b0[16], b1[16], b2[16];
    {
        const __hip_bfloat16* w0 = wcat + ((size_t)0 * NR + row) * KC + kbase;
        const __hip_bfloat16* w1 = wcat + ((size_t)1 * NR + row) * KC + kbase;
        const __hip_bfloat16* w2 = wcat + ((size_t)2 * NR + row) * KC + kbase;
        #pragma unroll
        for (int kb = 0; kb < 16; ++kb) {
            b0[kb] = *(const bf16x8*)(w0 + kb * 32);
            b1[kb] = *(const bf16x8*)(w1 + kb * 32);
            b2[kb] = *(const bf16x8*)(w2 + kb * 32);
        }
    }

    float c0a = 0.f, c0b = 0.f, c1a = 0.f, c1b = 0.f, c2a = 0.f, c2b = 0.f;
    unsigned gen = 1;

    auto stage = [&](const __hip_bfloat16* a1, const __hip_bfloat16* a2,
                     bool a1cached, const bf16x8 (&b)[16], const float* bias_l,
                     float& cA, float& cB, __hip_bfloat16* hcur_l,
                     int t, bool is_top, bool last_t,
                     float* hT_l, float* cT_l) {
        const __hip_bfloat16* apart = (wv < 2) ? a1 : a2;
        const bool cached = (wv < 2) ? a1cached : false;
        const int aoff = (wv & 1) * 512 + kgrp;
        f32x4 acc[4];
        #pragma unroll
        for (int mt = 0; mt < 4; ++mt) acc[mt] = f32x4{0.f, 0.f, 0.f, 0.f};
        if (cached) {
            #pragma unroll
            for (int mt = 0; mt < 4; ++mt) {
                const __hip_bfloat16* ar = apart + (size_t)(mt * 16 + nfr) * 1024 + aoff;
                #pragma unroll
                for (int kb = 0; kb < 16; ++kb)
                    acc[mt] = __builtin_amdgcn_mfma_f32_16x16x32_bf16(
                        *(const bf16x8*)(ar + kb * 32), b[kb], acc[mt], 0, 0, 0);
            }
        } else {
            #pragma unroll
            for (int mt = 0; mt < 4; ++mt) {
                const __hip_bfloat16* ar = apart + (size_t)(mt * 16 + nfr) * 1024 + aoff;
                #pragma unroll
                for (int kb = 0; kb < 16; ++kb)
                    acc[mt] = __builtin_amdgcn_mfma_f32_16x16x32_bf16(
                        aload_frag(ar + kb * 32), b[kb], acc[mt], 0, 0, 0);
            }
        }
        #pragma unroll
        for (int mt = 0; mt < 4; ++mt)
            #pragma unroll
            for (int j = 0; j < 4; ++j)
                part[wv][mt][nfr][mgrp + j] = acc[mt][j];
        __syncthreads();

        if (tid < 128) {
            float hn2[2], cn2[2];
            #pragma unroll
            for (int j = 0; j < 2; ++j) {
                const int ul = cp + j;
                const int cunit = U0 + ul;
                float gv[4];
                #pragma unroll
                for (int g = 0; g < 4; ++g) {
                    float s = bias_l[g * NH + cunit];
                    #pragma unroll
                    for (int w2 = 0; w2 < 4; ++w2)
                        s += part[w2][cm >> 4][g * 4 + ul][cm & 15];
                    gv[g] = s;
                }
                const float iv = 1.f / (1.f + __expf(-gv[0]));
                const float fv = 1.f / (1.f + __expf(-gv[1]));
                const float gg = 1.f - 2.f / (__expf(2.f * gv[2]) + 1.f);
                const float ov = 1.f / (1.f + __expf(-gv[3]));
                float& cref = (j == 0) ? cA : cB;
                const float cn = fv * cref + iv * gg;
                const float hn = ov * (1.f - 2.f / (__expf(2.f * cn) + 1.f));
                cref = cn;
                hn2[j] = hn; cn2[j] = cn;
            }
            const unsigned pk = (unsigned)bf16bits(hn2[0]) |
                                ((unsigned)bf16bits(hn2[1]) << 16);
            __hip_atomic_store((unsigned*)(hcur_l + cm * NH + U0 + cp), pk,
                               __ATOMIC_RELAXED, __HIP_MEMORY_SCOPE_AGENT);
            if (is_top) {
                outs[((size_t)cm * NT + t) * NH + U0 + cp]     = hn2[0];
                outs[((size_t)cm * NT + t) * NH + U0 + cp + 1] = hn2[1];
            }
            if (last_t) {
                hT_l[cm * NH + U0 + cp]     = hn2[0];
                hT_l[cm * NH + U0 + cp + 1] = hn2[1];
                cT_l[cm * NH + U0 + cp]     = cn2[0];
                cT_l[cm * NH + U0 + cp + 1] = cn2[1];
            }
        }
    };

    for (int t = 0; t < NT; ++t) {
        const __hip_bfloat16* hprev = (t & 1) ? hB : hA;
        __hip_bfloat16*       hcur  = (t & 1) ? hA : hB;
        const bool last_t = (t == NT - 1);

        stage(xbf + (size_t)t * NB * NE, hprev, true, b0, bias,
              c0a, c0b, hcur, t, false, last_t, hT, cT);
        grid_barrier(flags, release, bid, tid, gen++);

        stage(hcur, hprev + BH, false, b1, bias + NR,
              c1a, c1b, hcur + BH, t, false, last_t, hT + BH, cT + BH);
        grid_barrier(flags, release, bid, tid, gen++);

        stage(hcur + BH, hprev + 2 * BH, false, b2, bias + 2 * NR,
              c2a, c2b, hcur + 2 * BH, t, true, last_t,
              hT + 2 * BH, cT + 2 * BH);
    }
}

// ---------------- launcher ----------------

extern "C" void kernel_launch(void* const* d_in, const int* in_sizes, int n_in,
                              void* d_out, int out_size, void* d_ws, size_t ws_size,
                              hipStream_t stream) {
    const float* inputs = (const float*)d_in[0];
    const float* enc    = (const float*)d_in[1];
    const float* W_ih   = (const float*)d_in[2];
    const float* W_hh   = (const float*)d_in[3];
    const float* bias   = (const float*)d_in[4];
    float* out = (float*)d_out;

    const size_t need_rot  = (WCAT_E + XBF_E + HSEQ_E) * 2 + FLAGS_W * 4;
    const size_t need_dbuf = (WCAT_E + XBF_E + 2 * HBUF_E) * 2 + FLAGS_W * 4;

    __hip_bfloat16* wcat = (__hip_bfloat16*)d_ws;
    __hip_bfloat16* xbf  = wcat + WCAT_E;

    if (ws_size >= need_rot) {
        __hip_bfloat16* hseq  = xbf + XBF_E;
        unsigned*       flags = (unsigned*)(hseq + HSEQ_E);

        convert_w<<<dim3(4096), dim3(256), 0, stream>>>(W_ih, W_hh, wcat);
        convert_x<<<dim3(2048), dim3(256), 0, stream>>>(inputs, xbf);
        init_h<<<dim3(768), dim3(256), 0, stream>>>(enc, hseq, flags);

        lstm_rot<<<dim3(256), dim3(256), 0, stream>>>(
            bias, wcat, xbf, hseq, out, flags);
    } else if (ws_size >= need_dbuf) {
        __hip_bfloat16* hA    = xbf + XBF_E;
        __hip_bfloat16* hB    = hA + HBUF_E;
        unsigned*       flags = (unsigned*)(hB + HBUF_E);

        convert_w<<<dim3(4096), dim3(256), 0, stream>>>(W_ih, W_hh, wcat);
        convert_x<<<dim3(2048), dim3(256), 0, stream>>>(inputs, xbf);
        init_h<<<dim3(768), dim3(256), 0, stream>>>(enc, hA, flags);

        lstm_dbuf<<<dim3(256), dim3(256), 0, stream>>>(
            bias, wcat, xbf, hA, hB, out, flags);
    }
    // ws_size >= 84.7MB is proven by R7/R10-R12 passing runs, so one of the
    // two branches always executes.
}

// Round 14
// 8653.502 us; speedup vs baseline: 1.6979x; 1.3776x over previous
//
#include <hip/hip_runtime.h>
#include <hip/hip_bf16.h>

using bf16x8 = __attribute__((ext_vector_type(8))) short;  // 8 bf16, 4 VGPRs
using f32x4  = __attribute__((ext_vector_type(4))) float;

static constexpr int NB = 64, NT = 256, NE = 1024, NH = 1024, NL = 3;
static constexpr int NR = 4096, KC = 2048;
static constexpr int STATE = NL * NB * NH;             // 196608
static constexpr int BH = NB * NH;                     // 65536
static constexpr size_t WCAT_E = (size_t)NL * NR * KC;  // 25,165,824 bf16
static constexpr size_t XBF_E  = (size_t)NT * NB * NE;  // 16,777,216 bf16
static constexpr size_t HSEQ_E = (size_t)(NT + 1) * STATE;  // 50,528,256 bf16
static constexpr int FSTR  = 32;                       // u32s per flag slot (128B)
static constexpr int NFLAG = 256 * FSTR;
static constexpr int NREL  = 32 * FSTR;
static constexpr size_t FLAGS_W = NFLAG + NREL;

// ---------------- prologue kernels ----------------

__global__ void __launch_bounds__(256)
convert_w(const float* __restrict__ wih, const float* __restrict__ whh,
          __hip_bfloat16* __restrict__ wcat) {
    size_t i = (size_t)blockIdx.x * 256 + threadIdx.x;
    const size_t stride = (size_t)gridDim.x * 256;
    for (; i < WCAT_E; i += stride) {
        const int k = (int)(i & (KC - 1));
        const size_t lr = i >> 11;            // l*NR + r
        const int r = (int)(lr & (NR - 1));
        const int l = (int)(lr >> 12);
        const float v = (k < NE) ? wih[((size_t)l * NR + r) * NE + k]
                                 : whh[((size_t)l * NR + r) * NH + (k - NE)];
        wcat[i] = __float2bfloat16(v);
    }
}

__global__ void __launch_bounds__(256)
convert_x(const float* __restrict__ x, __hip_bfloat16* __restrict__ xbf) {
    size_t i = (size_t)blockIdx.x * 256 + threadIdx.x;
    const size_t stride = (size_t)gridDim.x * 256;
    for (; i < XBF_E; i += stride) {          // xbf[t][m][e] <- x[m][t][e]
        const int e = (int)(i & (NE - 1));
        const size_t tm = i >> 10;
        const int m = (int)(tm & (NB - 1));
        const int t = (int)(tm >> 6);
        xbf[i] = __float2bfloat16(x[((size_t)m * NT + t) * NE + e]);
    }
}

__global__ void __launch_bounds__(256)
init_h(const float* __restrict__ enc, __hip_bfloat16* __restrict__ h0,
       unsigned* __restrict__ flags) {
    const int i = blockIdx.x * 256 + threadIdx.x;     // 768 blocks
    if (i < STATE) h0[i] = __float2bfloat16(enc[i & (BH - 1)]);
    if (i < (int)FLAGS_W) flags[i] = 0u;
}

// ---------------- helpers ----------------

__device__ __forceinline__ unsigned short bf16bits(float f) {
    const __hip_bfloat16 h = __float2bfloat16(f);
    union { __hip_bfloat16 h; unsigned short s; } u{h};
    return u.s;
}

// ---------------- root-poll barrier (measured ~0.6us) ----------------
__device__ __forceinline__ void grid_barrier(unsigned* __restrict__ flags,
                                             unsigned* __restrict__ release,
                                             int bid, int tid, unsigned gen) {
    asm volatile("s_waitcnt vmcnt(0)" ::: "memory");
    __syncthreads();
    if (tid == 0)
        __hip_atomic_store(&flags[bid * FSTR], gen,
                           __ATOMIC_RELAXED, __HIP_MEMORY_SCOPE_AGENT);
    if (bid == 0) {
        for (;;) {
            const unsigned v = __hip_atomic_load(&flags[tid * FSTR],
                                  __ATOMIC_RELAXED, __HIP_MEMORY_SCOPE_AGENT);
            if (__all((int)(v >= gen))) break;
            __builtin_amdgcn_s_sleep(2);
        }
        __syncthreads();
        const int lane = tid & 63, wv = tid >> 6;
        if (lane < 8)
            __hip_atomic_store(&release[(wv * 8 + lane) * FSTR], gen,
                               __ATOMIC_RELAXED, __HIP_MEMORY_SCOPE_AGENT);
    } else {
        if (tid < 64) {
            for (;;) {
                const unsigned v = __hip_atomic_load(&release[(bid >> 3) * FSTR],
                                      __ATOMIC_RELAXED, __HIP_MEMORY_SCOPE_AGENT);
                if (v >= gen) break;
                __builtin_amdgcn_s_sleep(2);
            }
        }
        __syncthreads();
    }
}

#define LOAD16(dst, base)                                         \
    _Pragma("unroll")                                             \
    for (int kb = 0; kb < 16; ++kb)                               \
        dst[kb] = *(const bf16x8*)((base) + kb * 32);

#define MFMA16(accv, asrc, bsrc)                                  \
    _Pragma("unroll")                                             \
    for (int kb = 0; kb < 16; ++kb)                               \
        accv = __builtin_amdgcn_mfma_f32_16x16x32_bf16(           \
            asrc[kb], bsrc[kb], accv, 0, 0, 0);

// ---------------- rotating-buffer MFMA kernel (grid=256, normal launch) ----
// h(t) at hseq + t*STATE (never-reused addresses -> normal cached reads).
// Software-pipelined inner loop: 16 B-loads + double-buffered 16 A-loads
// issued ahead of MFMAs -> MLP ~16 instead of ~1.
__global__ void __launch_bounds__(256, 1)
lstm_rot(const float* __restrict__ bias,
         const __hip_bfloat16* __restrict__ wcat,
         const __hip_bfloat16* __restrict__ xbf,
         __hip_bfloat16* __restrict__ hseq,
         float* __restrict__ out,
         unsigned* __restrict__ flags)
{
    const int tid  = threadIdx.x;
    const int lane = tid & 63;
    const int wv   = tid >> 6;            // K-slice 0..3
    const int bid  = blockIdx.x;
    // XCD-swizzled unit group: blocks on one XCD own contiguous 128 units
    // -> 128B outs/h lines are written by a single XCD (no cross-XCD RFO).
    const int U0   = ((bid & 7) * 32 + (bid >> 3)) * 4;
    const int nfr  = lane & 15;           // frag col: g = nfr>>2, u = nfr&3
    const int kgrp = (lane >> 4) * 8;
    const int mgrp = (lane >> 4) * 4;
    const int cm   = tid >> 1;            // cell: batch (tid<128)
    const int cp   = (tid & 1) * 2;       // cell: unit pair offset

    float* hT   = out;
    float* cT   = out + STATE;
    float* outs = out + 2 * STATE;
    unsigned* release = flags + NFLAG;

    __shared__ float part[4][4][16][17];

    const int row   = (nfr >> 2) * NH + U0 + (nfr & 3);   // gate row
    const int kbase = (wv >= 2 ? 1024 : 0) + (wv & 1) * 512 + kgrp;
    const int aoff  = (wv & 1) * 512 + kgrp;

    float c0a = 0.f, c0b = 0.f, c1a = 0.f, c1b = 0.f, c2a = 0.f, c2b = 0.f;
    unsigned gen = 1;

    auto stage = [&](const __hip_bfloat16* a1, const __hip_bfloat16* a2,
                     const __hip_bfloat16* wl, const float* bias_l,
                     float& cA, float& cB, __hip_bfloat16* hw,
                     int t, bool is_top, bool last_t,
                     float* hT_l, float* cT_l) {
        const __hip_bfloat16* apart = (wv < 2) ? a1 : a2;
        const __hip_bfloat16* wp = wl + (size_t)row * KC + kbase;
        const __hip_bfloat16* ar0 = apart + (size_t)(0 * 16 + nfr) * 1024 + aoff;
        const __hip_bfloat16* ar1 = apart + (size_t)(1 * 16 + nfr) * 1024 + aoff;
        const __hip_bfloat16* ar2 = apart + (size_t)(2 * 16 + nfr) * 1024 + aoff;
        const __hip_bfloat16* ar3 = apart + (size_t)(3 * 16 + nfr) * 1024 + aoff;

        bf16x8 bfr[16], aX[16], aY[16];
        f32x4 acc0 = {0.f, 0.f, 0.f, 0.f}, acc1 = {0.f, 0.f, 0.f, 0.f};
        f32x4 acc2 = {0.f, 0.f, 0.f, 0.f}, acc3 = {0.f, 0.f, 0.f, 0.f};

        LOAD16(bfr, wp);            // 16 B-loads in flight
        LOAD16(aX, ar0);            // +16 A-loads (mt=0)
        LOAD16(aY, ar1);            // prefetch mt=1
        MFMA16(acc0, aX, bfr);      // waits only on aX/bfr
        LOAD16(aX, ar2);            // prefetch mt=2 (aX regs free after acc0)
        MFMA16(acc1, aY, bfr);
        LOAD16(aY, ar3);            // prefetch mt=3
        MFMA16(acc2, aX, bfr);
        MFMA16(acc3, aY, bfr);

        #pragma unroll
        for (int j = 0; j < 4; ++j) {
            part[wv][0][nfr][mgrp + j] = acc0[j];
            part[wv][1][nfr][mgrp + j] = acc1[j];
            part[wv][2][nfr][mgrp + j] = acc2[j];
            part[wv][3][nfr][mgrp + j] = acc3[j];
        }
        __syncthreads();

        if (tid < 128) {
            float hn2[2], cn2[2];
            #pragma unroll
            for (int j = 0; j < 2; ++j) {
                const int ul = cp + j;
                const int cunit = U0 + ul;
                float gv[4];
                #pragma unroll
                for (int g = 0; g < 4; ++g) {
                    float s = bias_l[g * NH + cunit];
                    #pragma unroll
                    for (int w2 = 0; w2 < 4; ++w2)
                        s += part[w2][cm >> 4][g * 4 + ul][cm & 15];
                    gv[g] = s;
                }
                const float iv = 1.f / (1.f + __expf(-gv[0]));
                const float fv = 1.f / (1.f + __expf(-gv[1]));
                const float gg = 1.f - 2.f / (__expf(2.f * gv[2]) + 1.f);
                const float ov = 1.f / (1.f + __expf(-gv[3]));
                float& cref = (j == 0) ? cA : cB;
                const float cn = fv * cref + iv * gg;
                const float hn = ov * (1.f - 2.f / (__expf(2.f * cn) + 1.f));
                cref = cn;
                hn2[j] = hn; cn2[j] = cn;
            }
            const unsigned pk = (unsigned)bf16bits(hn2[0]) |
                                ((unsigned)bf16bits(hn2[1]) << 16);
            __hip_atomic_store((unsigned*)(hw + cm * NH + U0 + cp), pk,
                               __ATOMIC_RELAXED, __HIP_MEMORY_SCOPE_AGENT);
            if (is_top) {
                outs[((size_t)cm * NT + t) * NH + U0 + cp]     = hn2[0];
                outs[((size_t)cm * NT + t) * NH + U0 + cp + 1] = hn2[1];
            }
            if (last_t) {
                hT_l[cm * NH + U0 + cp]     = hn2[0];
                hT_l[cm * NH + U0 + cp + 1] = hn2[1];
                cT_l[cm * NH + U0 + cp]     = cn2[0];
                cT_l[cm * NH + U0 + cp + 1] = cn2[1];
            }
        }
    };

    const __hip_bfloat16* w0 = wcat;
    const __hip_bfloat16* w1 = wcat + (size_t)1 * NR * KC;
    const __hip_bfloat16* w2 = wcat + (size_t)2 * NR * KC;

    for (int t = 0; t < NT; ++t) {
        __hip_bfloat16* Hp = hseq + (size_t)t * STATE;        // h after t steps
        __hip_bfloat16* Hc = hseq + (size_t)(t + 1) * STATE;  // written this step
        const bool last_t = (t == NT - 1);

        stage(xbf + (size_t)t * NB * NE, Hp, w0, bias,
              c0a, c0b, Hc, t, false, last_t, hT, cT);               // l=0
        grid_barrier(flags, release, bid, tid, gen++);

        stage(Hc, Hp + BH, w1, bias + NR,
              c1a, c1b, Hc + BH, t, false, last_t,
              hT + BH, cT + BH);                                     // l=1
        grid_barrier(flags, release, bid, tid, gen++);

        stage(Hc + BH, Hp + 2 * BH, w2, bias + 2 * NR,
              c2a, c2b, Hc + 2 * BH, t, true, last_t,
              hT + 2 * BH, cT + 2 * BH);                             // l=2
        // no barrier after l=2: t+1's l0/l1 barriers cover all RAW;
        // rotation means nothing is overwritten (no WAR).
    }
}

// ---------------- launcher ----------------

extern "C" void kernel_launch(void* const* d_in, const int* in_sizes, int n_in,
                              void* d_out, int out_size, void* d_ws, size_t ws_size,
                              hipStream_t stream) {
    const float* inputs = (const float*)d_in[0];
    const float* enc    = (const float*)d_in[1];
    const float* W_ih   = (const float*)d_in[2];
    const float* W_hh   = (const float*)d_in[3];
    const float* bias   = (const float*)d_in[4];
    float* out = (float*)d_out;

    __hip_bfloat16* wcat  = (__hip_bfloat16*)d_ws;
    __hip_bfloat16* xbf   = wcat + WCAT_E;
    __hip_bfloat16* hseq  = xbf + XBF_E;
    unsigned*       flags = (unsigned*)(hseq + HSEQ_E);
    // ws need ~185.4 MB: proven available by R13's passing lstm_rot run.

    convert_w<<<dim3(4096), dim3(256), 0, stream>>>(W_ih, W_hh, wcat);
    convert_x<<<dim3(2048), dim3(256), 0, stream>>>(inputs, xbf);
    init_h<<<dim3(768), dim3(256), 0, stream>>>(enc, hseq, flags);

    lstm_rot<<<dim3(256), dim3(256), 0, stream>>>(
        bias, wcat, xbf, hseq, out, flags);
}

// Round 15
// 8539.412 us; speedup vs baseline: 1.7206x; 1.0134x over previous
//
#include <hip/hip_runtime.h>
#include <hip/hip_bf16.h>

using bf16x8 = __attribute__((ext_vector_type(8))) short;  // 8 bf16, 4 VGPRs
using f32x4  = __attribute__((ext_vector_type(4))) float;

static constexpr int NB = 64, NT = 256, NE = 1024, NH = 1024, NL = 3;
static constexpr int NR = 4096, KC = 2048;
static constexpr int STATE = NL * NB * NH;             // 196608
static constexpr int BH = NB * NH;                     // 65536
static constexpr size_t WCAT_E = (size_t)NL * NR * KC;  // 25,165,824 bf16
static constexpr size_t XBF_E  = (size_t)NT * NB * NE;  // 16,777,216 bf16
static constexpr size_t HSEQ_E = (size_t)(NT + 1) * STATE;  // 50,528,256 bf16
static constexpr int FSTR  = 32;                       // u32s per flag slot (128B)
static constexpr int NFLAG = 256 * FSTR;
static constexpr int NREL  = 32 * FSTR;
static constexpr size_t FLAGS_W = NFLAG + NREL;

// ---------------- prologue kernels ----------------

__global__ void __launch_bounds__(256)
convert_w(const float* __restrict__ wih, const float* __restrict__ whh,
          __hip_bfloat16* __restrict__ wcat) {
    size_t i = (size_t)blockIdx.x * 256 + threadIdx.x;
    const size_t stride = (size_t)gridDim.x * 256;
    for (; i < WCAT_E; i += stride) {
        const int k = (int)(i & (KC - 1));
        const size_t lr = i >> 11;            // l*NR + r
        const int r = (int)(lr & (NR - 1));
        const int l = (int)(lr >> 12);
        const float v = (k < NE) ? wih[((size_t)l * NR + r) * NE + k]
                                 : whh[((size_t)l * NR + r) * NH + (k - NE)];
        wcat[i] = __float2bfloat16(v);
    }
}

__global__ void __launch_bounds__(256)
convert_x(const float* __restrict__ x, __hip_bfloat16* __restrict__ xbf) {
    size_t i = (size_t)blockIdx.x * 256 + threadIdx.x;
    const size_t stride = (size_t)gridDim.x * 256;
    for (; i < XBF_E; i += stride) {          // xbf[t][m][e] <- x[m][t][e]
        const int e = (int)(i & (NE - 1));
        const size_t tm = i >> 10;
        const int m = (int)(tm & (NB - 1));
        const int t = (int)(tm >> 6);
        xbf[i] = __float2bfloat16(x[((size_t)m * NT + t) * NE + e]);
    }
}

__global__ void __launch_bounds__(256)
init_h(const float* __restrict__ enc, __hip_bfloat16* __restrict__ h0,
       unsigned* __restrict__ flags) {
    const int i = blockIdx.x * 256 + threadIdx.x;     // 768 blocks
    if (i < STATE) h0[i] = __float2bfloat16(enc[i & (BH - 1)]);
    if (i < (int)FLAGS_W) flags[i] = 0u;
}

// ---------------- helpers ----------------

__device__ __forceinline__ unsigned short bf16bits(float f) {
    const __hip_bfloat16 h = __float2bfloat16(f);
    union { __hip_bfloat16 h; unsigned short s; } u{h};
    return u.s;
}

// ---------------- root-poll barrier (512-thread blocks) ----------------
__device__ __forceinline__ void grid_barrier(unsigned* __restrict__ flags,
                                             unsigned* __restrict__ release,
                                             int bid, int tid, unsigned gen) {
    asm volatile("s_waitcnt vmcnt(0)" ::: "memory");
    __syncthreads();
    if (tid == 0)
        __hip_atomic_store(&flags[bid * FSTR], gen,
                           __ATOMIC_RELAXED, __HIP_MEMORY_SCOPE_AGENT);
    const int lane = tid & 63, w = tid >> 6;
    if (bid == 0) {
        if (tid < 256) {                      // one flag per thread (4 waves)
            for (;;) {
                const unsigned v = __hip_atomic_load(&flags[tid * FSTR],
                                      __ATOMIC_RELAXED, __HIP_MEMORY_SCOPE_AGENT);
                if (__all((int)(v >= gen))) break;
                __builtin_amdgcn_s_sleep(2);
            }
        }
        __syncthreads();
        if (w < 4 && lane < 8)
            __hip_atomic_store(&release[(w * 8 + lane) * FSTR], gen,
                               __ATOMIC_RELAXED, __HIP_MEMORY_SCOPE_AGENT);
    } else {
        if (tid < 64) {
            for (;;) {
                const unsigned v = __hip_atomic_load(&release[(bid >> 3) * FSTR],
                                      __ATOMIC_RELAXED, __HIP_MEMORY_SCOPE_AGENT);
                if (v >= gen) break;
                __builtin_amdgcn_s_sleep(2);
            }
        }
        __syncthreads();
    }
}

#define LOAD8(dst, base)                                          \
    _Pragma("unroll")                                             \
    for (int kb = 0; kb < 8; ++kb)                                \
        dst[kb] = *(const bf16x8*)((base) + kb * 32);

#define MFMA8(accv, asrc, bsrc)                                   \
    _Pragma("unroll")                                             \
    for (int kb = 0; kb < 8; ++kb)                                \
        accv = __builtin_amdgcn_mfma_f32_16x16x32_bf16(           \
            asrc[kb], bsrc[kb], accv, 0, 0, 0);

// ---------------- rotating-buffer MFMA kernel (grid=256 x 512 thr) --------
// 8 waves/block (2/SIMD): k-slice 256 per wave -> TLP covers load latency.
// h(t) at hseq + t*STATE (fresh addresses -> normal cached reads).
__global__ void __launch_bounds__(512, 2)
lstm_rot(const float* __restrict__ bias,
         const __hip_bfloat16* __restrict__ wcat,
         const __hip_bfloat16* __restrict__ xbf,
         __hip_bfloat16* __restrict__ hseq,
         float* __restrict__ out,
         unsigned* __restrict__ flags)
{
    const int tid  = threadIdx.x;
    const int lane = tid & 63;
    const int wv   = tid >> 6;            // 0..7: waves 0-3 x-part, 4-7 h-part
    const int bid  = blockIdx.x;
    // XCD-swizzle: blocks on one XCD own contiguous 128 units.
    const int U0   = ((bid & 7) * 32 + (bid >> 3)) * 4;
    const int nfr  = lane & 15;           // frag col: g = nfr>>2, u = nfr&3
    const int kgrp = (lane >> 4) * 8;
    const int mgrp = (lane >> 4) * 4;
    const int cm   = tid >> 1;            // cell: batch (tid<128)
    const int cp   = (tid & 1) * 2;       // cell: unit pair offset

    float* hT   = out;
    float* cT   = out + STATE;
    float* outs = out + 2 * STATE;
    unsigned* release = flags + NFLAG;

    __shared__ float part[8][4][16][17];  // 34 KiB

    const bool xpart = (wv < 4);
    const int  ksl   = xpart ? wv : (wv - 4);      // k-slice within operand
    const int row    = (nfr >> 2) * NH + U0 + (nfr & 3);   // gate row
    const int kbase  = (xpart ? 0 : 1024) + ksl * 256 + kgrp;
    const int aoff   = ksl * 256 + kgrp;

    float c0a = 0.f, c0b = 0.f, c1a = 0.f, c1b = 0.f, c2a = 0.f, c2b = 0.f;
    unsigned gen = 1;

    auto stage = [&](const __hip_bfloat16* a1, const __hip_bfloat16* a2,
                     const __hip_bfloat16* wl, const float* bias_l,
                     float& cA, float& cB, __hip_bfloat16* hw,
                     int t, bool is_top, bool last_t,
                     float* hT_l, float* cT_l) {
        const __hip_bfloat16* apart = xpart ? a1 : a2;
        const __hip_bfloat16* wp  = wl + (size_t)row * KC + kbase;
        const __hip_bfloat16* ar0 = apart + (size_t)(0 * 16 + nfr) * 1024 + aoff;
        const __hip_bfloat16* ar1 = apart + (size_t)(1 * 16 + nfr) * 1024 + aoff;
        const __hip_bfloat16* ar2 = apart + (size_t)(2 * 16 + nfr) * 1024 + aoff;
        const __hip_bfloat16* ar3 = apart + (size_t)(3 * 16 + nfr) * 1024 + aoff;

        bf16x8 bfr[8], aX[8], aY[8];
        f32x4 acc0 = {0.f, 0.f, 0.f, 0.f}, acc1 = {0.f, 0.f, 0.f, 0.f};
        f32x4 acc2 = {0.f, 0.f, 0.f, 0.f}, acc3 = {0.f, 0.f, 0.f, 0.f};

        LOAD8(bfr, wp);             // 8 B-loads in flight
        LOAD8(aX, ar0);             // +8 A-loads (mt=0)
        LOAD8(aY, ar1);             // prefetch mt=1
        MFMA8(acc0, aX, bfr);
        LOAD8(aX, ar2);             // prefetch mt=2
        MFMA8(acc1, aY, bfr);
        LOAD8(aY, ar3);             // prefetch mt=3
        MFMA8(acc2, aX, bfr);
        MFMA8(acc3, aY, bfr);

        #pragma unroll
        for (int j = 0; j < 4; ++j) {
            part[wv][0][nfr][mgrp + j] = acc0[j];
            part[wv][1][nfr][mgrp + j] = acc1[j];
            part[wv][2][nfr][mgrp + j] = acc2[j];
            part[wv][3][nfr][mgrp + j] = acc3[j];
        }
        __syncthreads();

        if (tid < 128) {
            float hn2[2], cn2[2];
            #pragma unroll
            for (int j = 0; j < 2; ++j) {
                const int ul = cp + j;
                const int cunit = U0 + ul;
                float gv[4];
                #pragma unroll
                for (int g = 0; g < 4; ++g) {
                    float s = bias_l[g * NH + cunit];
                    #pragma unroll
                    for (int w2 = 0; w2 < 8; ++w2)
                        s += part[w2][cm >> 4][g * 4 + ul][cm & 15];
                    gv[g] = s;
                }
                const float iv = 1.f / (1.f + __expf(-gv[0]));
                const float fv = 1.f / (1.f + __expf(-gv[1]));
                const float gg = 1.f - 2.f / (__expf(2.f * gv[2]) + 1.f);
                const float ov = 1.f / (1.f + __expf(-gv[3]));
                float& cref = (j == 0) ? cA : cB;
                const float cn = fv * cref + iv * gg;
                const float hn = ov * (1.f - 2.f / (__expf(2.f * cn) + 1.f));
                cref = cn;
                hn2[j] = hn; cn2[j] = cn;
            }
            const unsigned pk = (unsigned)bf16bits(hn2[0]) |
                                ((unsigned)bf16bits(hn2[1]) << 16);
            __hip_atomic_store((unsigned*)(hw + cm * NH + U0 + cp), pk,
                               __ATOMIC_RELAXED, __HIP_MEMORY_SCOPE_AGENT);
            if (is_top) {
                outs[((size_t)cm * NT + t) * NH + U0 + cp]     = hn2[0];
                outs[((size_t)cm * NT + t) * NH + U0 + cp + 1] = hn2[1];
            }
            if (last_t) {
                hT_l[cm * NH + U0 + cp]     = hn2[0];
                hT_l[cm * NH + U0 + cp + 1] = hn2[1];
                cT_l[cm * NH + U0 + cp]     = cn2[0];
                cT_l[cm * NH + U0 + cp + 1] = cn2[1];
            }
        }
    };

    const __hip_bfloat16* w0 = wcat;
    const __hip_bfloat16* w1 = wcat + (size_t)1 * NR * KC;
    const __hip_bfloat16* w2 = wcat + (size_t)2 * NR * KC;

    for (int t = 0; t < NT; ++t) {
        __hip_bfloat16* Hp = hseq + (size_t)t * STATE;        // h after t steps
        __hip_bfloat16* Hc = hseq + (size_t)(t + 1) * STATE;  // written this step
        const bool last_t = (t == NT - 1);

        stage(xbf + (size_t)t * NB * NE, Hp, w0, bias,
              c0a, c0b, Hc, t, false, last_t, hT, cT);               // l=0
        grid_barrier(flags, release, bid, tid, gen++);

        stage(Hc, Hp + BH, w1, bias + NR,
              c1a, c1b, Hc + BH, t, false, last_t,
              hT + BH, cT + BH);                                     // l=1
        grid_barrier(flags, release, bid, tid, gen++);

        stage(Hc + BH, Hp + 2 * BH, w2, bias + 2 * NR,
              c2a, c2b, Hc + 2 * BH, t, true, last_t,
              hT + 2 * BH, cT + 2 * BH);                             // l=2
        // no barrier after l=2: t+1's l0/l1 barriers cover all RAW;
        // rotation means nothing is overwritten (no WAR).
    }
}

// ---------------- launcher ----------------

extern "C" void kernel_launch(void* const* d_in, const int* in_sizes, int n_in,
                              void* d_out, int out_size, void* d_ws, size_t ws_size,
                              hipStream_t stream) {
    const float* inputs = (const float*)d_in[0];
    const float* enc    = (const float*)d_in[1];
    const float* W_ih   = (const float*)d_in[2];
    const float* W_hh   = (const float*)d_in[3];
    const float* bias   = (const float*)d_in[4];
    float* out = (float*)d_out;

    __hip_bfloat16* wcat  = (__hip_bfloat16*)d_ws;
    __hip_bfloat16* xbf   = wcat + WCAT_E;
    __hip_bfloat16* hseq  = xbf + XBF_E;
    unsigned*       flags = (unsigned*)(hseq + HSEQ_E);
    // ws need ~185.4 MB: proven available by R13/R14 passing lstm_rot runs.

    convert_w<<<dim3(4096), dim3(256), 0, stream>>>(W_ih, W_hh, wcat);
    convert_x<<<dim3(2048), dim3(256), 0, stream>>>(inputs, xbf);
    init_h<<<dim3(768), dim3(256), 0, stream>>>(enc, hseq, flags);

    lstm_rot<<<dim3(256), dim3(512), 0, stream>>>(
        bias, wcat, xbf, hseq, out, flags);
}

// Round 16
// 4412.027 us; speedup vs baseline: 3.3302x; 1.9355x over previous
//
#include <hip/hip_runtime.h>
#include <hip/hip_bf16.h>

using bf16x8 = __attribute__((ext_vector_type(8))) short;  // 8 bf16, 4 VGPRs
using f32x4  = __attribute__((ext_vector_type(4))) float;

static constexpr int NB = 64, NT = 256, NE = 1024, NH = 1024, NL = 3;
static constexpr int NR = 4096, KC = 2048;
static constexpr int STATE = NL * NB * NH;             // 196608
static constexpr int BH = NB * NH;                     // 65536 (one panel)
static constexpr size_t WCAT_E = (size_t)NL * NR * KC;  // 25,165,824 bf16
static constexpr size_t XBF_E  = (size_t)NT * NB * NE;  // 16,777,216 bf16
static constexpr size_t HSEQ_E = (size_t)(NT + 1) * STATE;  // 50,528,256 bf16
static constexpr int FSTR  = 32;                       // u32s per flag slot (128B)
static constexpr int NFLAG = 256 * FSTR;
static constexpr int NREL  = 32 * FSTR;
static constexpr size_t FLAGS_W = NFLAG + NREL;

// Fragment-tiled panel layout (64 m x 1024 k bf16 = 32x4 tiles of 1KB):
//   off_e(m,k) = ((m>>4)*32 + (k>>5))*512 + (((k>>3)&3)*16 + (m&15))*8 + (k&7)
// A wave reading (mt, k-slice ksl) loads 8 contiguous 1KB tiles: base =
//   panel + (mt*32 + ksl*8)*512 + lane*8, stride 512 elems per k-block.
__host__ __device__ __forceinline__ size_t off_e(int m, int k) {
    return ((size_t)((m >> 4) * 32 + (k >> 5))) * 512 +
           (((k >> 3) & 3) * 16 + (m & 15)) * 8 + (k & 7);
}

// ---------------- prologue kernels ----------------

// wcat tiled: idx = ((((l*256+ug)*64 + kt)*64 + lane)*8 + e
//   nfr=lane&15, kg=lane>>4; row = (nfr>>2)*1024 + ug*4 + (nfr&3);
//   k = kt*32 + kg*8 + e  (k<1024 -> W_ih, else W_hh)
__global__ void __launch_bounds__(256)
convert_w(const float* __restrict__ wih, const float* __restrict__ whh,
          __hip_bfloat16* __restrict__ wcat) {
    size_t i = (size_t)blockIdx.x * 256 + threadIdx.x;
    const size_t stride = (size_t)gridDim.x * 256;
    for (; i < WCAT_E; i += stride) {
        const int e    = (int)(i & 7);
        const int lane = (int)((i >> 3) & 63);
        const int kt   = (int)((i >> 9) & 63);
        const int ug   = (int)((i >> 15) & 255);
        const int l    = (int)(i >> 23);
        const int nfr  = lane & 15, kg = lane >> 4;
        const int r    = (nfr >> 2) * 1024 + ug * 4 + (nfr & 3);
        const int k    = kt * 32 + kg * 8 + e;
        const float v = (k < NE) ? wih[((size_t)l * NR + r) * NE + k]
                                 : whh[((size_t)l * NR + r) * NH + (k - NE)];
        wcat[i] = __float2bfloat16(v);
    }
}

__global__ void __launch_bounds__(256)
convert_x(const float* __restrict__ x, __hip_bfloat16* __restrict__ xbf) {
    size_t i = (size_t)blockIdx.x * 256 + threadIdx.x;
    const size_t stride = (size_t)gridDim.x * 256;
    for (; i < XBF_E; i += stride) {          // enumerate (t, m, e)
        const int e = (int)(i & (NE - 1));
        const int m = (int)((i >> 10) & 63);
        const int t = (int)(i >> 16);
        xbf[(size_t)t * BH + off_e(m, e)] =
            __float2bfloat16(x[((size_t)m * NT + t) * NE + e]);
    }
}

__global__ void __launch_bounds__(256)
init_h(const float* __restrict__ enc, __hip_bfloat16* __restrict__ h0,
       unsigned* __restrict__ flags) {
    const int i = blockIdx.x * 256 + threadIdx.x;     // 768 blocks, i < STATE
    if (i < STATE) {
        const int u = i & 1023, m = (i >> 10) & 63, l = i >> 16;
        h0[(size_t)l * BH + off_e(m, u)] = __float2bfloat16(enc[m * NH + u]);
    }
    if (i < (int)FLAGS_W) flags[i] = 0u;
}

// ---------------- helpers ----------------

__device__ __forceinline__ unsigned short bf16bits(float f) {
    const __hip_bfloat16 h = __float2bfloat16(f);
    union { __hip_bfloat16 h; unsigned short s; } u{h};
    return u.s;
}

// ---------------- root-poll barrier (512-thread blocks, ~0.6us) ----------
__device__ __forceinline__ void grid_barrier(unsigned* __restrict__ flags,
                                             unsigned* __restrict__ release,
                                             int bid, int tid, unsigned gen) {
    asm volatile("s_waitcnt vmcnt(0)" ::: "memory");
    __syncthreads();
    if (tid == 0)
        __hip_atomic_store(&flags[bid * FSTR], gen,
                           __ATOMIC_RELAXED, __HIP_MEMORY_SCOPE_AGENT);
    const int lane = tid & 63, w = tid >> 6;
    if (bid == 0) {
        if (tid < 256) {
            for (;;) {
                const unsigned v = __hip_atomic_load(&flags[tid * FSTR],
                                      __ATOMIC_RELAXED, __HIP_MEMORY_SCOPE_AGENT);
                if (__all((int)(v >= gen))) break;
                __builtin_amdgcn_s_sleep(2);
            }
        }
        __syncthreads();
        if (w < 4 && lane < 8)
            __hip_atomic_store(&release[(w * 8 + lane) * FSTR], gen,
                               __ATOMIC_RELAXED, __HIP_MEMORY_SCOPE_AGENT);
    } else {
        if (tid < 64) {
            for (;;) {
                const unsigned v = __hip_atomic_load(&release[(bid >> 3) * FSTR],
                                      __ATOMIC_RELAXED, __HIP_MEMORY_SCOPE_AGENT);
                if (v >= gen) break;
                __builtin_amdgcn_s_sleep(2);
            }
        }
        __syncthreads();
    }
}

#define LOAD8S(dst, base)                                         \
    _Pragma("unroll")                                             \
    for (int kb = 0; kb < 8; ++kb)                                \
        dst[kb] = *(const bf16x8*)((base) + kb * 512);

#define MFMA8(accv, asrc, bsrc)                                   \
    _Pragma("unroll")                                             \
    for (int kb = 0; kb < 8; ++kb)                                \
        accv = __builtin_amdgcn_mfma_f32_16x16x32_bf16(           \
            asrc[kb], bsrc[kb], accv, 0, 0, 0);

// ---------------- layer-pipelined rotating-buffer MFMA kernel -------------
// Step s: l0(t=s) | l1(t=s-1) | l2(t=s-2). All cross-block inputs were
// written at step s-1 -> ONE barrier per step (257 total vs 512).
// All panels fragment-tiled -> every wave load = 1KB contiguous.
__global__ void __launch_bounds__(512, 2)
lstm_pipe(const float* __restrict__ bias,
          const __hip_bfloat16* __restrict__ wcat,
          const __hip_bfloat16* __restrict__ xbf,
          __hip_bfloat16* __restrict__ hseq,
          float* __restrict__ out,
          unsigned* __restrict__ flags)
{
    const int tid  = threadIdx.x;
    const int lane = tid & 63;
    const int wv   = tid >> 6;            // 0..7: waves 0-3 x-part, 4-7 h-part
    const int bid  = blockIdx.x;
    const int ug   = (bid & 7) * 32 + (bid >> 3);   // XCD-swizzled unit group
    const int U0   = ug * 4;
    const int nfr  = lane & 15;
    const int mgrp = (lane >> 4) * 4;
    const int cm   = tid >> 1;            // cell: batch (tid<128)
    const int cp   = (tid & 1) * 2;       // cell: unit pair offset

    float* hT   = out;
    float* cT   = out + STATE;
    float* outs = out + 2 * STATE;
    unsigned* release = flags + NFLAG;

    __shared__ float part[8][4][16][17];  // 34.8 KiB

    const bool xpart = (wv < 4);
    const int  ksl   = xpart ? wv : (wv - 4);   // k-slice within operand panel

    float c0a = 0.f, c0b = 0.f, c1a = 0.f, c1b = 0.f, c2a = 0.f, c2b = 0.f;
    unsigned gen = 1;

    // a1/a2/hw are fragment-tiled panels (BH elems each)
    auto stage = [&](const __hip_bfloat16* a1, const __hip_bfloat16* a2,
                     const __hip_bfloat16* wl, const float* bias_l,
                     float& cA, float& cB, __hip_bfloat16* hw,
                     int t, bool is_top, bool last_t,
                     float* hT_l, float* cT_l) {
        const __hip_bfloat16* apart = xpart ? a1 : a2;
        // weights: 8 contiguous 1KB tiles for (ug, wv)
        const __hip_bfloat16* wp  = wl + ((size_t)ug * 64 + wv * 8) * 512 + lane * 8;
        const __hip_bfloat16* ar0 = apart + ((size_t)(0 * 32 + ksl * 8)) * 512 + lane * 8;
        const __hip_bfloat16* ar1 = apart + ((size_t)(1 * 32 + ksl * 8)) * 512 + lane * 8;
        const __hip_bfloat16* ar2 = apart + ((size_t)(2 * 32 + ksl * 8)) * 512 + lane * 8;
        const __hip_bfloat16* ar3 = apart + ((size_t)(3 * 32 + ksl * 8)) * 512 + lane * 8;

        bf16x8 bfr[8], aX[8], aY[8];
        f32x4 acc0 = {0.f, 0.f, 0.f, 0.f}, acc1 = {0.f, 0.f, 0.f, 0.f};
        f32x4 acc2 = {0.f, 0.f, 0.f, 0.f}, acc3 = {0.f, 0.f, 0.f, 0.f};

        LOAD8S(bfr, wp);
        LOAD8S(aX, ar0);
        LOAD8S(aY, ar1);
        MFMA8(acc0, aX, bfr);
        LOAD8S(aX, ar2);
        MFMA8(acc1, aY, bfr);
        LOAD8S(aY, ar3);
        MFMA8(acc2, aX, bfr);
        MFMA8(acc3, aY, bfr);

        #pragma unroll
        for (int j = 0; j < 4; ++j) {
            part[wv][0][nfr][mgrp + j] = acc0[j];
            part[wv][1][nfr][mgrp + j] = acc1[j];
            part[wv][2][nfr][mgrp + j] = acc2[j];
            part[wv][3][nfr][mgrp + j] = acc3[j];
        }
        __syncthreads();

        if (tid < 128) {
            float hn2[2], cn2[2];
            #pragma unroll
            for (int j = 0; j < 2; ++j) {
                const int ul = cp + j;
                const int cunit = U0 + ul;
                float gv[4];
                #pragma unroll
                for (int g = 0; g < 4; ++g) {
                    float s = bias_l[g * NH + cunit];
                    #pragma unroll
                    for (int w2 = 0; w2 < 8; ++w2)
                        s += part[w2][cm >> 4][g * 4 + ul][cm & 15];
                    gv[g] = s;
                }
                const float iv = 1.f / (1.f + __expf(-gv[0]));
                const float fv = 1.f / (1.f + __expf(-gv[1]));
                const float gg = 1.f - 2.f / (__expf(2.f * gv[2]) + 1.f);
                const float ov = 1.f / (1.f + __expf(-gv[3]));
                float& cref = (j == 0) ? cA : cB;
                const float cn = fv * cref + iv * gg;
                const float hn = ov * (1.f - 2.f / (__expf(2.f * cn) + 1.f));
                cref = cn;
                hn2[j] = hn; cn2[j] = cn;
            }
            // tiled packed write (u even -> 4B-aligned slot)
            const int u = U0 + cp;
            const size_t off = ((size_t)((cm >> 4) * 32 + (u >> 5))) * 512 +
                               (((u >> 3) & 3) * 16 + (cm & 15)) * 8 + (u & 7);
            const unsigned pk = (unsigned)bf16bits(hn2[0]) |
                                ((unsigned)bf16bits(hn2[1]) << 16);
            __hip_atomic_store((unsigned*)(hw + off), pk,
                               __ATOMIC_RELAXED, __HIP_MEMORY_SCOPE_AGENT);
            if (is_top) {
                outs[((size_t)cm * NT + t) * NH + u]     = hn2[0];
                outs[((size_t)cm * NT + t) * NH + u + 1] = hn2[1];
            }
            if (last_t) {
                hT_l[cm * NH + u]     = hn2[0];
                hT_l[cm * NH + u + 1] = hn2[1];
                cT_l[cm * NH + u]     = cn2[0];
                cT_l[cm * NH + u + 1] = cn2[1];
            }
        }
        __syncthreads();
    };

    const __hip_bfloat16* w0 = wcat;
    const __hip_bfloat16* w1 = wcat + (size_t)1 * NR * KC;
    const __hip_bfloat16* w2 = wcat + (size_t)2 * NR * KC;

    for (int s = 0; s < NT + 2; ++s) {
        if (s < NT) {                                   // l0, t0 = s
            const int t0 = s;
            stage(xbf + (size_t)t0 * BH,
                  hseq + (size_t)t0 * STATE,
                  w0, bias, c0a, c0b,
                  hseq + (size_t)(t0 + 1) * STATE,
                  t0, false, t0 == NT - 1, hT, cT);
        }
        if (s >= 1 && s <= NT) {                        // l1, t1 = s-1
            const int t1 = s - 1;
            stage(hseq + (size_t)(t1 + 1) * STATE,      // h^0(t1), step s-1
                  hseq + (size_t)t1 * STATE + BH,       // h^1(t1-1), step s-1
                  w1, bias + NR, c1a, c1b,
                  hseq + (size_t)(t1 + 1) * STATE + BH,
                  t1, false, t1 == NT - 1, hT + BH, cT + BH);
        }
        if (s >= 2) {                                   // l2, t2 = s-2
            const int t2 = s - 2;
            stage(hseq + (size_t)(t2 + 1) * STATE + BH,
                  hseq + (size_t)t2 * STATE + 2 * BH,
                  w2, bias + 2 * NR, c2a, c2b,
                  hseq + (size_t)(t2 + 1) * STATE + 2 * BH,
                  t2, true, t2 == NT - 1, hT + 2 * BH, cT + 2 * BH);
        }
        if (s < NT + 1) grid_barrier(flags, release, bid, tid, gen++);
    }
}

// ---------------- launcher ----------------

extern "C" void kernel_launch(void* const* d_in, const int* in_sizes, int n_in,
                              void* d_out, int out_size, void* d_ws, size_t ws_size,
                              hipStream_t stream) {
    const float* inputs = (const float*)d_in[0];
    const float* enc    = (const float*)d_in[1];
    const float* W_ih   = (const float*)d_in[2];
    const float* W_hh   = (const float*)d_in[3];
    const float* bias   = (const float*)d_in[4];
    float* out = (float*)d_out;

    __hip_bfloat16* wcat  = (__hip_bfloat16*)d_ws;
    __hip_bfloat16* xbf   = wcat + WCAT_E;
    __hip_bfloat16* hseq  = xbf + XBF_E;
    unsigned*       flags = (unsigned*)(hseq + HSEQ_E);
    // ws need ~185.4 MB: proven by R13-R15 passing runs.

    convert_w<<<dim3(4096), dim3(256), 0, stream>>>(W_ih, W_hh, wcat);
    convert_x<<<dim3(2048), dim3(256), 0, stream>>>(inputs, xbf);
    init_h<<<dim3(768), dim3(256), 0, stream>>>(enc, hseq, flags);

    lstm_pipe<<<dim3(256), dim3(512), 0, stream>>>(
        bias, wcat, xbf, hseq, out, flags);
}

// Round 17
// 3129.439 us; speedup vs baseline: 4.6950x; 1.4098x over previous
//
#include <hip/hip_runtime.h>
#include <hip/hip_bf16.h>

using bf16x8 = __attribute__((ext_vector_type(8))) short;  // 8 bf16, 4 VGPRs
using f32x4  = __attribute__((ext_vector_type(4))) float;

static constexpr int NB = 64, NT = 256, NE = 1024, NH = 1024, NL = 3;
static constexpr int NR = 4096, KC = 2048;
static constexpr int STATE = NL * NB * NH;             // 196608
static constexpr int BH = NB * NH;                     // 65536 (one panel)
static constexpr size_t WCAT_E = (size_t)NL * NR * KC;  // 25,165,824 bf16
static constexpr size_t XBF_E  = (size_t)NT * NB * NE;  // 16,777,216 bf16
static constexpr size_t HSEQ_E = (size_t)(NT + 1) * STATE;  // 50,528,256 bf16
static constexpr int FSTR  = 32;                       // u32s per flag slot (128B)
static constexpr int NFLAG = 256 * FSTR;
static constexpr int NREL  = 32 * FSTR;
static constexpr size_t FLAGS_W = NFLAG + NREL;
static constexpr size_t PART_BYTES = 3u * 8 * 4 * 16 * 16 * 4;   // 98304 (96KB)

// Fragment-tiled panel layout (64 m x 1024 k bf16 = 32x4 tiles of 1KB):
__host__ __device__ __forceinline__ size_t off_e(int m, int k) {
    return ((size_t)((m >> 4) * 32 + (k >> 5))) * 512 +
           (((k >> 3) & 3) * 16 + (m & 15)) * 8 + (k & 7);
}

// ---------------- prologue kernels (unchanged from R16) ----------------

__global__ void __launch_bounds__(256)
convert_w(const float* __restrict__ wih, const float* __restrict__ whh,
          __hip_bfloat16* __restrict__ wcat) {
    size_t i = (size_t)blockIdx.x * 256 + threadIdx.x;
    const size_t stride = (size_t)gridDim.x * 256;
    for (; i < WCAT_E; i += stride) {
        const int e    = (int)(i & 7);
        const int lane = (int)((i >> 3) & 63);
        const int kt   = (int)((i >> 9) & 63);
        const int ug   = (int)((i >> 15) & 255);
        const int l    = (int)(i >> 23);
        const int nfr  = lane & 15, kg = lane >> 4;
        const int r    = (nfr >> 2) * 1024 + ug * 4 + (nfr & 3);
        const int k    = kt * 32 + kg * 8 + e;
        const float v = (k < NE) ? wih[((size_t)l * NR + r) * NE + k]
                                 : whh[((size_t)l * NR + r) * NH + (k - NE)];
        wcat[i] = __float2bfloat16(v);
    }
}

__global__ void __launch_bounds__(256)
convert_x(const float* __restrict__ x, __hip_bfloat16* __restrict__ xbf) {
    size_t i = (size_t)blockIdx.x * 256 + threadIdx.x;
    const size_t stride = (size_t)gridDim.x * 256;
    for (; i < XBF_E; i += stride) {
        const int e = (int)(i & (NE - 1));
        const int m = (int)((i >> 10) & 63);
        const int t = (int)(i >> 16);
        xbf[(size_t)t * BH + off_e(m, e)] =
            __float2bfloat16(x[((size_t)m * NT + t) * NE + e]);
    }
}

__global__ void __launch_bounds__(256)
init_h(const float* __restrict__ enc, __hip_bfloat16* __restrict__ h0,
       unsigned* __restrict__ flags) {
    const int i = blockIdx.x * 256 + threadIdx.x;
    if (i < STATE) {
        const int u = i & 1023, m = (i >> 10) & 63, l = i >> 16;
        h0[(size_t)l * BH + off_e(m, u)] = __float2bfloat16(enc[m * NH + u]);
    }
    if (i < (int)FLAGS_W) flags[i] = 0u;
}

// ---------------- helpers ----------------

__device__ __forceinline__ unsigned short bf16bits(float f) {
    const __hip_bfloat16 h = __float2bfloat16(f);
    union { __hip_bfloat16 h; unsigned short s; } u{h};
    return u.s;
}

// ---------------- root-poll barrier (~0.6us) ----------------
__device__ __forceinline__ void grid_barrier(unsigned* __restrict__ flags,
                                             unsigned* __restrict__ release,
                                             int bid, int tid, unsigned gen) {
    asm volatile("s_waitcnt vmcnt(0)" ::: "memory");
    __syncthreads();
    if (tid == 0)
        __hip_atomic_store(&flags[bid * FSTR], gen,
                           __ATOMIC_RELAXED, __HIP_MEMORY_SCOPE_AGENT);
    const int lane = tid & 63, w = tid >> 6;
    if (bid == 0) {
        if (tid < 256) {
            for (;;) {
                const unsigned v = __hip_atomic_load(&flags[tid * FSTR],
                                      __ATOMIC_RELAXED, __HIP_MEMORY_SCOPE_AGENT);
                if (__all((int)(v >= gen))) break;
                __builtin_amdgcn_s_sleep(2);
            }
        }
        __syncthreads();
        if (w < 4 && lane < 8)
            __hip_atomic_store(&release[(w * 8 + lane) * FSTR], gen,
                               __ATOMIC_RELAXED, __HIP_MEMORY_SCOPE_AGENT);
    } else {
        if (tid < 64) {
            for (;;) {
                const unsigned v = __hip_atomic_load(&release[(bid >> 3) * FSTR],
                                      __ATOMIC_RELAXED, __HIP_MEMORY_SCOPE_AGENT);
                if (v >= gen) break;
                __builtin_amdgcn_s_sleep(2);
            }
        }
        __syncthreads();
    }
}

#define LOAD8S(dst, base)                                         \
    _Pragma("unroll")                                             \
    for (int kb = 0; kb < 8; ++kb)                                \
        dst[kb] = *(const bf16x8*)((base) + kb * 512);

#define MFMA8(accv, asrc, bsrc)                                   \
    _Pragma("unroll")                                             \
    for (int kb = 0; kb < 8; ++kb)                                \
        accv = __builtin_amdgcn_mfma_f32_16x16x32_bf16(           \
            asrc[kb], bsrc[kb], accv, 0, 0, 0);

#define SB __builtin_amdgcn_sched_barrier(0)

#define ZEROACC                                                    \
    acc0 = f32x4{0.f, 0.f, 0.f, 0.f}; acc1 = f32x4{0.f, 0.f, 0.f, 0.f}; \
    acc2 = f32x4{0.f, 0.f, 0.f, 0.f}; acc3 = f32x4{0.f, 0.f, 0.f, 0.f};

// part index: [st][w][mt][m][n], unpadded (96KB dynamic LDS)
__device__ __forceinline__ int pidx(int st, int w, int mt, int m, int n) {
    return (((st * 8 + w) * 4 + mt) * 16 + m) * 16 + n;
}
#define STOREP(st)                                                 \
    _Pragma("unroll")                                              \
    for (int j = 0; j < 4; ++j) {                                  \
        part[pidx(st, wv, 0, mgrp + j, nfr)] = acc0[j];            \
        part[pidx(st, wv, 1, mgrp + j, nfr)] = acc1[j];            \
        part[pidx(st, wv, 2, mgrp + j, nfr)] = acc2[j];            \
        part[pidx(st, wv, 3, mgrp + j, nfr)] = acc3[j];            \
    }

// ---------------- fused 3-layer pipelined MFMA kernel --------------------
// Step s: l0(t=s) | l1(t=s-1) | l2(t=s-2), all inputs ready at step start.
// ONE MFMA phase (120 rolling loads/wave), ONE syncthreads, wide cell phase,
// ONE grid barrier. Boundary steps run the same path with clamped t.
__global__ void __launch_bounds__(512, 2)
lstm_pipe(const float* __restrict__ bias,
          const __hip_bfloat16* __restrict__ wcat,
          const __hip_bfloat16* __restrict__ xbf,
          __hip_bfloat16* __restrict__ hseq,
          float* __restrict__ out,
          unsigned* __restrict__ flags)
{
    extern __shared__ float part[];
    const int tid  = threadIdx.x;
    const int lane = tid & 63;
    const int wv   = tid >> 6;            // 0..7: waves 0-3 x-part, 4-7 h-part
    const int bid  = blockIdx.x;
    const int ug   = (bid & 7) * 32 + (bid >> 3);   // XCD-swizzled unit group
    const int U0   = ug * 4;
    const int nfr  = lane & 15;
    const int mgrp = (lane >> 4) * 4;

    float* hT   = out;
    float* cT   = out + STATE;
    float* outs = out + 2 * STATE;
    unsigned* release = flags + NFLAG;

    const bool xpart = (wv < 4);
    const int  ksl   = xpart ? wv : (wv - 4);

    const __hip_bfloat16* wp0 = wcat + ((size_t)ug * 64 + wv * 8) * 512 + lane * 8;
    const __hip_bfloat16* wp1 = wp0 + (size_t)1 * NR * KC;
    const __hip_bfloat16* wp2 = wp0 + (size_t)2 * NR * KC;
    const size_t lane8 = (size_t)(ksl * 8) * 512 + lane * 8;

    float cA = 0.f, cB = 0.f;             // cell state (tid<384: layer tid>>7)
    unsigned gen = 1;

    for (int s = 0; s < NT + 2; ++s) {
        const int t0 = (s < NT) ? s : NT - 1;
        const int t1c = (s - 1 < 0) ? 0 : ((s - 1 < NT) ? s - 1 : NT - 1);
        const int t2c = (s - 2 < 0) ? 0 : ((s - 2 < NT) ? s - 2 : NT - 1);

        const __hip_bfloat16* ap0 = xpart ? (xbf + (size_t)t0 * BH)
                                          : (hseq + (size_t)t0 * STATE);
        const __hip_bfloat16* ap1 = xpart ? (hseq + (size_t)(t1c + 1) * STATE)
                                          : (hseq + (size_t)t1c * STATE + BH);
        const __hip_bfloat16* ap2 = xpart ? (hseq + (size_t)(t2c + 1) * STATE + BH)
                                          : (hseq + (size_t)t2c * STATE + 2 * BH);
        const __hip_bfloat16* a00 = ap0 + lane8;            // mt stride 32*512
        const __hip_bfloat16* a10 = ap1 + lane8;
        const __hip_bfloat16* a20 = ap2 + lane8;

        bf16x8 bA[8], bB[8], aX[8], aY[8];
        f32x4 acc0, acc1, acc2, acc3;

        // ---- rolling load/MFMA pipeline over 3 layers ----
        LOAD8S(bA, wp0);
        LOAD8S(aX, a00 + 0 * 32 * 512);
        LOAD8S(aY, a00 + 1 * 32 * 512);
        LOAD8S(bB, wp1);
        SB;
        ZEROACC;
        MFMA8(acc0, aX, bA); SB; LOAD8S(aX, a00 + 2 * 32 * 512); SB;
        MFMA8(acc1, aY, bA); SB; LOAD8S(aY, a00 + 3 * 32 * 512); SB;
        MFMA8(acc2, aX, bA); SB; LOAD8S(aX, a10 + 0 * 32 * 512); SB;
        MFMA8(acc3, aY, bA); SB; LOAD8S(aY, a10 + 1 * 32 * 512);
                                 LOAD8S(bA, wp2); SB;
        STOREP(0);
        ZEROACC;
        MFMA8(acc0, aX, bB); SB; LOAD8S(aX, a10 + 2 * 32 * 512); SB;
        MFMA8(acc1, aY, bB); SB; LOAD8S(aY, a10 + 3 * 32 * 512); SB;
        MFMA8(acc2, aX, bB); SB; LOAD8S(aX, a20 + 0 * 32 * 512); SB;
        MFMA8(acc3, aY, bB); SB; LOAD8S(aY, a20 + 1 * 32 * 512); SB;
        STOREP(1);
        ZEROACC;
        MFMA8(acc0, aX, bA); SB; LOAD8S(aX, a20 + 2 * 32 * 512); SB;
        MFMA8(acc1, aY, bA); SB; LOAD8S(aY, a20 + 3 * 32 * 512); SB;
        MFMA8(acc2, aX, bA); SB;
        MFMA8(acc3, aY, bA); SB;
        STOREP(2);
        __syncthreads();

        // ---- cell phase: 384 threads, one layer each ----
        if (tid < 384) {
            const int st = tid >> 7, r = tid & 127;
            const int t  = s - st;
            if (t >= 0 && t < NT) {
                const int cm = r >> 1, cp = (r & 1) * 2;
                const float* bias_l = bias + (size_t)st * NR;
                float hn2[2], cn2[2];
                #pragma unroll
                for (int j = 0; j < 2; ++j) {
                    const int ul = cp + j;
                    const int cunit = U0 + ul;
                    float gv[4];
                    #pragma unroll
                    for (int g = 0; g < 4; ++g) {
                        float ssum = bias_l[g * NH + cunit];
                        #pragma unroll
                        for (int w2 = 0; w2 < 8; ++w2)
                            ssum += part[pidx(st, w2, cm >> 4, cm & 15, g * 4 + ul)];
                        gv[g] = ssum;
                    }
                    const float iv = 1.f / (1.f + __expf(-gv[0]));
                    const float fv = 1.f / (1.f + __expf(-gv[1]));
                    const float gg = 1.f - 2.f / (__expf(2.f * gv[2]) + 1.f);
                    const float ov = 1.f / (1.f + __expf(-gv[3]));
                    float& cref = (j == 0) ? cA : cB;
                    const float cn = fv * cref + iv * gg;
                    const float hn = ov * (1.f - 2.f / (__expf(2.f * cn) + 1.f));
                    cref = cn;
                    hn2[j] = hn; cn2[j] = cn;
                }
                __hip_bfloat16* hw = hseq + (size_t)(t + 1) * STATE + st * BH;
                const int u = U0 + cp;
                const size_t off = ((size_t)((cm >> 4) * 32 + (u >> 5))) * 512 +
                                   (((u >> 3) & 3) * 16 + (cm & 15)) * 8 + (u & 7);
                const unsigned pk = (unsigned)bf16bits(hn2[0]) |
                                    ((unsigned)bf16bits(hn2[1]) << 16);
                __hip_atomic_store((unsigned*)(hw + off), pk,
                                   __ATOMIC_RELAXED, __HIP_MEMORY_SCOPE_AGENT);
                if (st == 2) {
                    outs[((size_t)cm * NT + t) * NH + u]     = hn2[0];
                    outs[((size_t)cm * NT + t) * NH + u + 1] = hn2[1];
                }
                if (t == NT - 1) {
                    float* hT_l = hT + st * BH;
                    float* cT_l = cT + st * BH;
                    hT_l[cm * NH + u]     = hn2[0];
                    hT_l[cm * NH + u + 1] = hn2[1];
                    cT_l[cm * NH + u]     = cn2[0];
                    cT_l[cm * NH + u + 1] = cn2[1];
                }
            }
        }
        if (s < NT + 1) grid_barrier(flags, release, bid, tid, gen++);
    }
}

// ---------------- launcher ----------------

extern "C" void kernel_launch(void* const* d_in, const int* in_sizes, int n_in,
                              void* d_out, int out_size, void* d_ws, size_t ws_size,
                              hipStream_t stream) {
    const float* inputs = (const float*)d_in[0];
    const float* enc    = (const float*)d_in[1];
    const float* W_ih   = (const float*)d_in[2];
    const float* W_hh   = (const float*)d_in[3];
    const float* bias   = (const float*)d_in[4];
    float* out = (float*)d_out;

    __hip_bfloat16* wcat  = (__hip_bfloat16*)d_ws;
    __hip_bfloat16* xbf   = wcat + WCAT_E;
    __hip_bfloat16* hseq  = xbf + XBF_E;
    unsigned*       flags = (unsigned*)(hseq + HSEQ_E);
    // ws need ~185.4 MB: proven by R13-R16 passing runs.

    (void)hipFuncSetAttribute((const void*)lstm_pipe,
                              hipFuncAttributeMaxDynamicSharedMemorySize,
                              (int)PART_BYTES);

    convert_w<<<dim3(4096), dim3(256), 0, stream>>>(W_ih, W_hh, wcat);
    convert_x<<<dim3(2048), dim3(256), 0, stream>>>(inputs, xbf);
    init_h<<<dim3(768), dim3(256), 0, stream>>>(enc, hseq, flags);

    lstm_pipe<<<dim3(256), dim3(512), PART_BYTES, stream>>>(
        bias, wcat, xbf, hseq, out, flags);
}

// Round 18
// 2912.464 us; speedup vs baseline: 5.0448x; 1.0745x over previous
//
#include <hip/hip_runtime.h>
#include <hip/hip_bf16.h>

using bf16x8 = __attribute__((ext_vector_type(8))) short;  // 8 bf16, 4 VGPRs
using f32x4  = __attribute__((ext_vector_type(4))) float;

static constexpr int NB = 64, NT = 256, NE = 1024, NH = 1024, NL = 3;
static constexpr int NR = 4096, KC = 2048;
static constexpr int STATE = NL * NB * NH;             // 196608
static constexpr int BH = NB * NH;                     // 65536 (one panel)
static constexpr size_t WCAT_E = (size_t)NL * NR * KC;  // 25,165,824 bf16
static constexpr size_t XBF_E  = (size_t)NT * NB * NE;  // 16,777,216 bf16
static constexpr size_t HSEQ_E = (size_t)(NT + 1) * STATE;  // 50,528,256 bf16
static constexpr int FSTR  = 32;                       // u32s per flag slot (128B)
static constexpr int NFLAG = 256 * FSTR;
static constexpr int NREL  = 32 * FSTR;
static constexpr size_t FLAGS_W = NFLAG + NREL;
static constexpr int PSTR = 18;                        // padded n-stride (2-way banks)
static constexpr size_t PART_BYTES = 3u * 8 * 4 * 16 * PSTR * 4;   // 110,592 B

// Fragment-tiled panel layout (64 m x 1024 k bf16 = 32x4 tiles of 1KB):
__host__ __device__ __forceinline__ size_t off_e(int m, int k) {
    return ((size_t)((m >> 4) * 32 + (k >> 5))) * 512 +
           (((k >> 3) & 3) * 16 + (m & 15)) * 8 + (k & 7);
}

// ---------------- prologue kernels (unchanged) ----------------

__global__ void __launch_bounds__(256)
convert_w(const float* __restrict__ wih, const float* __restrict__ whh,
          __hip_bfloat16* __restrict__ wcat) {
    size_t i = (size_t)blockIdx.x * 256 + threadIdx.x;
    const size_t stride = (size_t)gridDim.x * 256;
    for (; i < WCAT_E; i += stride) {
        const int e    = (int)(i & 7);
        const int lane = (int)((i >> 3) & 63);
        const int kt   = (int)((i >> 9) & 63);
        const int ug   = (int)((i >> 15) & 255);
        const int l    = (int)(i >> 23);
        const int nfr  = lane & 15, kg = lane >> 4;
        const int r    = (nfr >> 2) * 1024 + ug * 4 + (nfr & 3);
        const int k    = kt * 32 + kg * 8 + e;
        const float v = (k < NE) ? wih[((size_t)l * NR + r) * NE + k]
                                 : whh[((size_t)l * NR + r) * NH + (k - NE)];
        wcat[i] = __float2bfloat16(v);
    }
}

__global__ void __launch_bounds__(256)
convert_x(const float* __restrict__ x, __hip_bfloat16* __restrict__ xbf) {
    size_t i = (size_t)blockIdx.x * 256 + threadIdx.x;
    const size_t stride = (size_t)gridDim.x * 256;
    for (; i < XBF_E; i += stride) {
        const int e = (int)(i & (NE - 1));
        const int m = (int)((i >> 10) & 63);
        const int t = (int)(i >> 16);
        xbf[(size_t)t * BH + off_e(m, e)] =
            __float2bfloat16(x[((size_t)m * NT + t) * NE + e]);
    }
}

__global__ void __launch_bounds__(256)
init_h(const float* __restrict__ enc, __hip_bfloat16* __restrict__ h0,
       unsigned* __restrict__ flags) {
    const int i = blockIdx.x * 256 + threadIdx.x;
    if (i < STATE) {
        const int u = i & 1023, m = (i >> 10) & 63, l = i >> 16;
        h0[(size_t)l * BH + off_e(m, u)] = __float2bfloat16(enc[m * NH + u]);
    }
    if (i < (int)FLAGS_W) flags[i] = 0u;
}

// ---------------- helpers ----------------

__device__ __forceinline__ unsigned short bf16bits(float f) {
    const __hip_bfloat16 h = __float2bfloat16(f);
    union { __hip_bfloat16 h; unsigned short s; } u{h};
    return u.s;
}

// ---------------- root-poll barrier (~0.6us) ----------------
__device__ __forceinline__ void grid_barrier(unsigned* __restrict__ flags,
                                             unsigned* __restrict__ release,
                                             int bid, int tid, unsigned gen) {
    asm volatile("s_waitcnt vmcnt(0)" ::: "memory");
    __syncthreads();
    if (tid == 0)
        __hip_atomic_store(&flags[bid * FSTR], gen,
                           __ATOMIC_RELAXED, __HIP_MEMORY_SCOPE_AGENT);
    const int lane = tid & 63, w = tid >> 6;
    if (bid == 0) {
        if (tid < 256) {
            for (;;) {
                const unsigned v = __hip_atomic_load(&flags[tid * FSTR],
                                      __ATOMIC_RELAXED, __HIP_MEMORY_SCOPE_AGENT);
                if (__all((int)(v >= gen))) break;
                __builtin_amdgcn_s_sleep(2);
            }
        }
        __syncthreads();
        if (w < 4 && lane < 8)
            __hip_atomic_store(&release[(w * 8 + lane) * FSTR], gen,
                               __ATOMIC_RELAXED, __HIP_MEMORY_SCOPE_AGENT);
    } else {
        if (tid < 64) {
            for (;;) {
                const unsigned v = __hip_atomic_load(&release[(bid >> 3) * FSTR],
                                      __ATOMIC_RELAXED, __HIP_MEMORY_SCOPE_AGENT);
                if (v >= gen) break;
                __builtin_amdgcn_s_sleep(2);
            }
        }
        __syncthreads();
    }
}

#define LOAD8S(dst, base)                                         \
    _Pragma("unroll")                                             \
    for (int kb = 0; kb < 8; ++kb)                                \
        dst[kb] = *(const bf16x8*)((base) + kb * 512);

#define MFMA8(accv, asrc, bsrc)                                   \
    _Pragma("unroll")                                             \
    for (int kb = 0; kb < 8; ++kb)                                \
        accv = __builtin_amdgcn_mfma_f32_16x16x32_bf16(           \
            asrc[kb], bsrc[kb], accv, 0, 0, 0);

#define SB __builtin_amdgcn_sched_barrier(0)

#define ZEROACC                                                    \
    acc0 = f32x4{0.f, 0.f, 0.f, 0.f}; acc1 = f32x4{0.f, 0.f, 0.f, 0.f}; \
    acc2 = f32x4{0.f, 0.f, 0.f, 0.f}; acc3 = f32x4{0.f, 0.f, 0.f, 0.f};

// part index: [st][w][mt][m][n(PSTR=18 pad -> 2-way banks, free)]
__device__ __forceinline__ int pidx(int st, int w, int mt, int m, int n) {
    return (((st * 8 + w) * 4 + mt) * 16 + m) * PSTR + n;
}
#define STOREP(st)                                                 \
    _Pragma("unroll")                                              \
    for (int j = 0; j < 4; ++j) {                                  \
        part[pidx(st, wv, 0, mgrp + j, nfr)] = acc0[j];            \
        part[pidx(st, wv, 1, mgrp + j, nfr)] = acc1[j];            \
        part[pidx(st, wv, 2, mgrp + j, nfr)] = acc2[j];            \
        part[pidx(st, wv, 3, mgrp + j, nfr)] = acc3[j];            \
    }

// ---------------- fused 3-layer pipelined MFMA kernel --------------------
// Step s: l0(t=s) | l1(t=s-1) | l2(t=s-2). 5 rolling buffers (bA,bB,aX,aY,aZ
// = 160 VGPR of frags) -> each load has >=2 MFMA clusters before its use.
__global__ void __launch_bounds__(512, 2)
lstm_pipe(const float* __restrict__ bias,
          const __hip_bfloat16* __restrict__ wcat,
          const __hip_bfloat16* __restrict__ xbf,
          __hip_bfloat16* __restrict__ hseq,
          float* __restrict__ out,
          unsigned* __restrict__ flags)
{
    extern __shared__ float part[];
    const int tid  = threadIdx.x;
    const int lane = tid & 63;
    const int wv   = tid >> 6;            // 0..7: waves 0-3 x-part, 4-7 h-part
    const int bid  = blockIdx.x;
    const int ug   = (bid & 7) * 32 + (bid >> 3);   // XCD-swizzled unit group
    const int U0   = ug * 4;
    const int nfr  = lane & 15;
    const int mgrp = (lane >> 4) * 4;

    float* hT   = out;
    float* cT   = out + STATE;
    float* outs = out + 2 * STATE;
    unsigned* release = flags + NFLAG;

    const bool xpart = (wv < 4);
    const int  ksl   = xpart ? wv : (wv - 4);

    const __hip_bfloat16* wp0 = wcat + ((size_t)ug * 64 + wv * 8) * 512 + lane * 8;
    const __hip_bfloat16* wp1 = wp0 + (size_t)1 * NR * KC;
    const __hip_bfloat16* wp2 = wp0 + (size_t)2 * NR * KC;
    const size_t lane8 = (size_t)(ksl * 8) * 512 + lane * 8;

    float cA = 0.f, cB = 0.f;
    unsigned gen = 1;

    for (int s = 0; s < NT + 2; ++s) {
        const int t0 = (s < NT) ? s : NT - 1;
        const int t1c = (s - 1 < 0) ? 0 : ((s - 1 < NT) ? s - 1 : NT - 1);
        const int t2c = (s - 2 < 0) ? 0 : ((s - 2 < NT) ? s - 2 : NT - 1);

        const __hip_bfloat16* ap0 = xpart ? (xbf + (size_t)t0 * BH)
                                          : (hseq + (size_t)t0 * STATE);
        const __hip_bfloat16* ap1 = xpart ? (hseq + (size_t)(t1c + 1) * STATE)
                                          : (hseq + (size_t)t1c * STATE + BH);
        const __hip_bfloat16* ap2 = xpart ? (hseq + (size_t)(t2c + 1) * STATE + BH)
                                          : (hseq + (size_t)t2c * STATE + 2 * BH);
        const __hip_bfloat16* a00 = ap0 + lane8;            // mt stride 32*512
        const __hip_bfloat16* a10 = ap1 + lane8;
        const __hip_bfloat16* a20 = ap2 + lane8;

        bf16x8 bA[8], bB[8], aX[8], aY[8], aZ[8];
        f32x4 acc0, acc1, acc2, acc3;

        // ---- rolling 3-deep load/MFMA pipeline over 3 layers ----
        LOAD8S(bA, wp0);
        LOAD8S(aX, a00 + 0 * 32 * 512);
        LOAD8S(aY, a00 + 1 * 32 * 512);
        LOAD8S(aZ, a00 + 2 * 32 * 512);
        LOAD8S(bB, wp1);
        SB;
        ZEROACC;
        MFMA8(acc0, aX, bA); SB; LOAD8S(aX, a00 + 3 * 32 * 512); SB;
        MFMA8(acc1, aY, bA); SB; LOAD8S(aY, a10 + 0 * 32 * 512); SB;
        MFMA8(acc2, aZ, bA); SB; LOAD8S(aZ, a10 + 1 * 32 * 512); SB;
        MFMA8(acc3, aX, bA); SB; LOAD8S(aX, a10 + 2 * 32 * 512);
                                 LOAD8S(bA, wp2); SB;
        STOREP(0);
        ZEROACC;
        MFMA8(acc0, aY, bB); SB; LOAD8S(aY, a10 + 3 * 32 * 512); SB;
        MFMA8(acc1, aZ, bB); SB; LOAD8S(aZ, a20 + 0 * 32 * 512); SB;
        MFMA8(acc2, aX, bB); SB; LOAD8S(aX, a20 + 1 * 32 * 512); SB;
        MFMA8(acc3, aY, bB); SB; LOAD8S(aY, a20 + 2 * 32 * 512); SB;
        STOREP(1);
        ZEROACC;
        MFMA8(acc0, aZ, bA); SB; LOAD8S(aZ, a20 + 3 * 32 * 512); SB;
        MFMA8(acc1, aX, bA); SB;
        MFMA8(acc2, aY, bA); SB;
        MFMA8(acc3, aZ, bA); SB;
        STOREP(2);
        __syncthreads();

        // ---- cell phase: 384 threads, one layer each ----
        if (tid < 384) {
            const int st = tid >> 7, r = tid & 127;
            const int t  = s - st;
            if (t >= 0 && t < NT) {
                const int cm = r >> 1, cp = (r & 1) * 2;
                const float* bias_l = bias + (size_t)st * NR;
                float hn2[2], cn2[2];
                #pragma unroll
                for (int j = 0; j < 2; ++j) {
                    const int ul = cp + j;
                    const int cunit = U0 + ul;
                    float gv[4];
                    #pragma unroll
                    for (int g = 0; g < 4; ++g) {
                        float ssum = bias_l[g * NH + cunit];
                        #pragma unroll
                        for (int w2 = 0; w2 < 8; ++w2)
                            ssum += part[pidx(st, w2, cm >> 4, cm & 15, g * 4 + ul)];
                        gv[g] = ssum;
                    }
                    const float iv = 1.f / (1.f + __expf(-gv[0]));
                    const float fv = 1.f / (1.f + __expf(-gv[1]));
                    const float gg = 1.f - 2.f / (__expf(2.f * gv[2]) + 1.f);
                    const float ov = 1.f / (1.f + __expf(-gv[3]));
                    float& cref = (j == 0) ? cA : cB;
                    const float cn = fv * cref + iv * gg;
                    const float hn = ov * (1.f - 2.f / (__expf(2.f * cn) + 1.f));
                    cref = cn;
                    hn2[j] = hn; cn2[j] = cn;
                }
                __hip_bfloat16* hw = hseq + (size_t)(t + 1) * STATE + st * BH;
                const int u = U0 + cp;
                const size_t off = ((size_t)((cm >> 4) * 32 + (u >> 5))) * 512 +
                                   (((u >> 3) & 3) * 16 + (cm & 15)) * 8 + (u & 7);
                const unsigned pk = (unsigned)bf16bits(hn2[0]) |
                                    ((unsigned)bf16bits(hn2[1]) << 16);
                __hip_atomic_store((unsigned*)(hw + off), pk,
                                   __ATOMIC_RELAXED, __HIP_MEMORY_SCOPE_AGENT);
                if (st == 2) {
                    outs[((size_t)cm * NT + t) * NH + u]     = hn2[0];
                    outs[((size_t)cm * NT + t) * NH + u + 1] = hn2[1];
                }
                if (t == NT - 1) {
                    float* hT_l = hT + st * BH;
                    float* cT_l = cT + st * BH;
                    hT_l[cm * NH + u]     = hn2[0];
                    hT_l[cm * NH + u + 1] = hn2[1];
                    cT_l[cm * NH + u]     = cn2[0];
                    cT_l[cm * NH + u + 1] = cn2[1];
                }
            }
        }
        if (s < NT + 1) grid_barrier(flags, release, bid, tid, gen++);
    }
}

// ---------------- launcher ----------------

extern "C" void kernel_launch(void* const* d_in, const int* in_sizes, int n_in,
                              void* d_out, int out_size, void* d_ws, size_t ws_size,
                              hipStream_t stream) {
    const float* inputs = (const float*)d_in[0];
    const float* enc    = (const float*)d_in[1];
    const float* W_ih   = (const float*)d_in[2];
    const float* W_hh   = (const float*)d_in[3];
    const float* bias   = (const float*)d_in[4];
    float* out = (float*)d_out;

    __hip_bfloat16* wcat  = (__hip_bfloat16*)d_ws;
    __hip_bfloat16* xbf   = wcat + WCAT_E;
    __hip_bfloat16* hseq  = xbf + XBF_E;
    unsigned*       flags = (unsigned*)(hseq + HSEQ_E);
    // ws need ~185.4 MB: proven by R13-R17 passing runs.

    (void)hipFuncSetAttribute((const void*)lstm_pipe,
                              hipFuncAttributeMaxDynamicSharedMemorySize,
                              (int)PART_BYTES);

    convert_w<<<dim3(4096), dim3(256), 0, stream>>>(W_ih, W_hh, wcat);
    convert_x<<<dim3(2048), dim3(256), 0, stream>>>(inputs, xbf);
    init_h<<<dim3(768), dim3(256), 0, stream>>>(enc, hseq, flags);

    lstm_pipe<<<dim3(256), dim3(512), PART_BYTES, stream>>>(
        bias, wcat, xbf, hseq, out, flags);
}